// Round 15
// baseline (383.629 us; speedup 1.0000x reference)
//
#include <hip/hip_runtime.h>
#include <hip/hip_bf16.h>

#define SEQ 2048
#define DM 2048
#define NH 16
#define DK 128
#define LOG2E 1.4426950408889634f
#define QK_SCALE 0.08838834764831845f   // 128^-0.5

typedef __attribute__((ext_vector_type(8))) short short8;
typedef __attribute__((ext_vector_type(4))) float f32x4;
typedef __attribute__((ext_vector_type(4))) unsigned short us4;

__device__ __forceinline__ unsigned short f2b(float f) {
  union { float f; unsigned u; } v; v.f = f;
  unsigned r = v.u + 0x7fffu + ((v.u >> 16) & 1u);
  return (unsigned short)(r >> 16);
}
__device__ __forceinline__ float b2f(unsigned short v) {
  union { unsigned u; float f; } x; x.u = ((unsigned)v) << 16; return x.f;
}

__device__ __forceinline__ void gl_lds16(const void* g, void* l) {
  __builtin_amdgcn_global_load_lds((const __attribute__((address_space(1))) void*)g,
                                   (__attribute__((address_space(3))) void*)l, 16, 0, 0);
}

#define SBAR()   __builtin_amdgcn_s_barrier()
#define SCHED0() __builtin_amdgcn_sched_barrier(0)
#define LGKM0()  asm volatile("s_waitcnt lgkmcnt(0)" ::: "memory")

// ---------------- fused cast f32 -> bf16: states (4096 blk) + bias (4096 blk) ----------
__global__ __launch_bounds__(256) void cast2_bf16_kernel(const float* __restrict__ in0,
                                                         unsigned short* __restrict__ out0,
                                                         const float* __restrict__ in1,
                                                         unsigned short* __restrict__ out1) {
  int bid = blockIdx.x;
  const float* in = (bid < 4096) ? in0 : in1;
  unsigned short* out = (bid < 4096) ? out0 : out1;
  int i = ((bid < 4096) ? bid : bid - 4096) * 256 + threadIdx.x;
  const float4* p = (const float4*)in;
  float4 a = p[2*i], b = p[2*i+1];
  us4 r0, r1;
  r0[0]=f2b(a.x); r0[1]=f2b(a.y); r0[2]=f2b(a.z); r0[3]=f2b(a.w);
  r1[0]=f2b(b.x); r1[1]=f2b(b.y); r1[2]=f2b(b.z); r1[3]=f2b(b.w);
  us4* o = (us4*)out;
  o[2*i] = r0; o[2*i+1] = r1;
}

// ---------------- fused transpose+cast: 4 x w[2048][2048] f32 -> wt = w^T bf16 ----------
__global__ __launch_bounds__(256) void transpose_cast4_kernel(const float* __restrict__ w0,
                                                              const float* __restrict__ w1,
                                                              const float* __restrict__ w2,
                                                              const float* __restrict__ w3,
                                                              unsigned short* __restrict__ dst) {
  const float* w = (blockIdx.z == 0) ? w0 : (blockIdx.z == 1) ? w1 : (blockIdx.z == 2) ? w2 : w3;
  unsigned short* wt = dst + (size_t)blockIdx.z * DM * DM;
  __shared__ float t[64][65];
  int c0 = blockIdx.x * 64, r0 = blockIdx.y * 64;
  int tid = threadIdx.x;
  int rr = tid >> 4;
  int c4 = (tid & 15) * 4;
#pragma unroll
  for (int p = 0; p < 4; ++p) {
    int r = p*16 + rr;
    float4 v = *(const float4*)&w[(size_t)(r0 + r)*DM + c0 + c4];
    t[r][c4] = v.x; t[r][c4+1] = v.y; t[r][c4+2] = v.z; t[r][c4+3] = v.w;
  }
  __syncthreads();
#pragma unroll
  for (int p = 0; p < 4; ++p) {
    int c = p*16 + rr;
    us4 v;
    v[0] = f2b(t[c4+0][c]); v[1] = f2b(t[c4+1][c]);
    v[2] = f2b(t[c4+2][c]); v[3] = f2b(t[c4+3][c]);
    *(us4*)&wt[(size_t)(c0 + c)*DM + r0 + c4] = v;
  }
}

// ---------------- transpose + cast wg[2048][16] f32 -> wgT[16][2048] bf16 ----------------
__global__ __launch_bounds__(256) void transpose_wg_kernel(const float* __restrict__ wg,
                                                           unsigned short* __restrict__ wgT) {
  int idx = blockIdx.x * 256 + threadIdx.x;
  int c = idx & 15;
  int r0 = (idx >> 4) * 4;
#pragma unroll
  for (int r = 0; r < 4; ++r)
    wgT[(size_t)c*DM + r0 + r] = f2b(wg[(size_t)(r0 + r)*NH + c]);
}

// ================= 128x128 / BK=64 / 4-wave / 2-phase GEMM core — 2 blocks/CU ===========
__device__ __forceinline__ void gemm128x128_core(const unsigned short* __restrict__ A,
                                                 const unsigned short* __restrict__ Bt,
                                                 int m0, int n0, f32x4 (&acc)[4][4]) {
  __shared__ __align__(16) unsigned short Ab[2][8192];
  __shared__ __align__(16) unsigned short Bb[2][8192];
  const int TK = DM / 64;   // 32 K-steps

  int tid = threadIdx.x, wid = tid >> 6, lane = tid & 63;
  int lo = lane & 15, hi = lane >> 4;
  int wm = wid >> 1, wn = wid & 1;

  int srow8 = lane >> 3;
  int skb = (((lane & 7) ^ srow8) << 4);
  const char* Ag = (const char*)A;
  const char* Bg = (const char*)Bt;

#define STG_A(S,CUR) do {                                                          \
    const char* g = Ag + (size_t)(S)*128 + skb;                                    \
    char* l = (char*)&Ab[CUR][0] + wid*4096;                                       \
    _Pragma("unroll")                                                              \
    for (int c = 0; c < 4; ++c)                                                    \
      gl_lds16(g + (size_t)(m0 + wid*32 + c*8 + srow8)*4096, l + c*1024);          \
  } while(0)
#define STG_B(S,CUR) do {                                                          \
    const char* g = Bg + (size_t)(S)*128 + skb;                                    \
    char* l = (char*)&Bb[CUR][0] + wid*4096;                                       \
    _Pragma("unroll")                                                              \
    for (int c = 0; c < 4; ++c)                                                    \
      gl_lds16(g + (size_t)(n0 + wid*32 + c*8 + srow8)*4096, l + c*1024);          \
  } while(0)

#pragma unroll
  for (int i = 0; i < 4; ++i)
#pragma unroll
    for (int j = 0; j < 4; ++j) acc[i][j] = (f32x4){0.f,0.f,0.f,0.f};

  STG_B(0,0); STG_A(0,0); STG_B(1,1); STG_A(1,1);
  asm volatile("s_waitcnt vmcnt(8)" ::: "memory");
  SBAR();

  int msk = (lo & 7) << 4;
  int k0 = (hi*16) ^ msk;
  int k1 = (64 + hi*16) ^ msk;

  short8 a[4][2], bA[2][2], bB[2][2];

#define MF16(NHH,BF)                                                                \
  __builtin_amdgcn_s_setprio(1);                                                    \
  _Pragma("unroll") for (int mi = 0; mi < 4; ++mi)                                  \
  _Pragma("unroll") for (int nn = 0; nn < 2; ++nn) {                                \
    acc[mi][(NHH)*2+nn] = __builtin_amdgcn_mfma_f32_16x16x32_bf16(                  \
        a[mi][0], BF[nn][0], acc[mi][(NHH)*2+nn], 0, 0, 0);                         \
    acc[mi][(NHH)*2+nn] = __builtin_amdgcn_mfma_f32_16x16x32_bf16(                  \
        a[mi][1], BF[nn][1], acc[mi][(NHH)*2+nn], 0, 0, 0);                         \
  }                                                                                 \
  __builtin_amdgcn_s_setprio(0);

  for (int s = 0; s < TK; ++s) {
    int cur = s & 1;
    const char* Ac = (const char*)&Ab[cur][0];
    const char* Bc = (const char*)&Bb[cur][0];
    bool pre = (s + 2) < TK;

#pragma unroll
    for (int mm = 0; mm < 4; ++mm) {
      a[mm][0] = *(const short8*)(Ac + (wm*64 + mm*16 + lo)*128 + k0);
      a[mm][1] = *(const short8*)(Ac + (wm*64 + mm*16 + lo)*128 + k1);
    }
#pragma unroll
    for (int nn = 0; nn < 2; ++nn) {
      bA[nn][0] = *(const short8*)(Bc + (wn*64 + nn*16 + lo)*128 + k0);
      bA[nn][1] = *(const short8*)(Bc + (wn*64 + nn*16 + lo)*128 + k1);
      bB[nn][0] = *(const short8*)(Bc + (wn*64 + (2+nn)*16 + lo)*128 + k0);
      bB[nn][1] = *(const short8*)(Bc + (wn*64 + (2+nn)*16 + lo)*128 + k1);
    }
    SBAR(); LGKM0(); SCHED0();
    MF16(0, bA);
    SBAR();

    if (pre) {
      STG_B(s + 2, cur);
      STG_A(s + 2, cur);
      asm volatile("s_waitcnt vmcnt(8)" ::: "memory");
    } else if (s == TK - 2) {
      asm volatile("s_waitcnt vmcnt(0)" ::: "memory");
    }
    SBAR();
    MF16(1, bB);
    SBAR();
  }
#undef STG_A
#undef STG_B
#undef MF16
}

// ---------------- fused QKV GEMM: A(4096x2048) x WQVT(6144x2048)^T, grid 48x32 --------
__global__ __launch_bounds__(256, 2) void gemm128_qkv_kernel(const unsigned short* __restrict__ A,
                                                             const unsigned short* __restrict__ Bt,
                                                             const float* __restrict__ bq,
                                                             const float* __restrict__ bk,
                                                             const float* __restrict__ bv,
                                                             unsigned short* __restrict__ QB,
                                                             unsigned short* __restrict__ KB,
                                                             unsigned short* __restrict__ VTB) {
  f32x4 acc[4][4];
  int n0 = blockIdx.x * 128, m0 = blockIdx.y * 128;
  gemm128x128_core(A, Bt, m0, n0, acc);

  int tid = threadIdx.x, wid = tid >> 6, lane = tid & 63;
  int lo = lane & 15, hi = lane >> 4;
  int wm = wid >> 1, wn = wid & 1;
  int m_base = m0 + wm*64;
  int n_base = n0 + wn*64;
  int sect = n0 >> 11;

  if (sect == 2) {       // V -> transposed [b,h,d,s]
#pragma unroll
    for (int mi = 0; mi < 4; ++mi) {
      int m = m_base + mi*16 + 4*hi;
      int b = m >> 11, srow = m & 2047;
#pragma unroll
      for (int nf = 0; nf < 4; ++nf) {
        int n = n_base + nf*16 + lo;
        int nl = n & 2047, h = nl >> 7, d = nl & 127;
        float bvv = bv[nl];
        us4 pk;
#pragma unroll
        for (int r = 0; r < 4; ++r) pk[r] = f2b(acc[mi][nf][r] + bvv);
        *(us4*)&VTB[(((size_t)(b*NH + h))*DK + d)*SEQ + srow] = pk;
      }
    }
  } else {
    unsigned short* out = sect ? KB : QB;
    const float* bp = sect ? bk : bq;
    const float qs = sect ? 1.f : QK_SCALE * LOG2E;
#pragma unroll
    for (int mi = 0; mi < 4; ++mi) {
#pragma unroll
      for (int nf = 0; nf < 4; ++nf) {
        int n = n_base + nf*16 + lo;
        int nl = n & 2047, h = nl >> 7, d = nl & 127;
        float bvv = bp[nl];
#pragma unroll
        for (int r = 0; r < 4; ++r) {
          int m = m_base + mi*16 + 4*hi + r;
          int b = m >> 11, srow = m & 2047;
          out[(((size_t)(b*NH + h))*SEQ + srow)*DK + d] = f2b((acc[mi][nf][r] + bvv) * qs);
        }
      }
    }
  }
}

// ---------------- AO GEMM: grid 16x32 = 512 blocks = 1 full round at 2/CU --------------
__global__ __launch_bounds__(256, 2) void gemm128_ao_kernel(const unsigned short* __restrict__ A,
                                                            const unsigned short* __restrict__ Bt,
                                                            const float* __restrict__ bias,
                                                            float* __restrict__ out) {
  f32x4 acc[4][4];
  int n0 = blockIdx.x * 128, m0 = blockIdx.y * 128;
  gemm128x128_core(A, Bt, m0, n0, acc);

  int tid = threadIdx.x, wid = tid >> 6, lane = tid & 63;
  int lo = lane & 15, hi = lane >> 4;
  int wm = wid >> 1, wn = wid & 1;
#pragma unroll
  for (int mi = 0; mi < 4; ++mi) {
#pragma unroll
    for (int nf = 0; nf < 4; ++nf) {
      int n = n0 + wn*64 + nf*16 + lo;
      float bvv = bias[n];
#pragma unroll
      for (int r = 0; r < 4; ++r) {
        int m = m0 + wm*64 + mi*16 + 4*hi + r;
        out[(size_t)m*DM + n] = acc[mi][nf][r] + bvv;
      }
    }
  }
}

// ---------------- gate via MFMA: G[m][h] = sigmoid(XB[m]·wgT[h] + bg[h]) ----------------
__global__ __launch_bounds__(256) void gate_mfma_kernel(const unsigned short* __restrict__ XB,
                                                        const unsigned short* __restrict__ wgT,
                                                        const float* __restrict__ bg,
                                                        float* __restrict__ G) {
  int tid = threadIdx.x, wid = tid >> 6, lane = tid & 63;
  int lo = lane & 15, hi = lane >> 4;
  int m0 = blockIdx.x * 64 + wid * 16;

  f32x4 acc = {0.f, 0.f, 0.f, 0.f};
  const unsigned short* xrow = XB + (size_t)(m0 + lo) * DM + hi * 8;
  const unsigned short* grow = wgT + (size_t)lo * DM + hi * 8;
#pragma unroll 4
  for (int kt = 0; kt < DM; kt += 32) {
    short8 a = *(const short8*)(xrow + kt);
    short8 b = *(const short8*)(grow + kt);
    acc = __builtin_amdgcn_mfma_f32_16x16x32_bf16(a, b, acc, 0, 0, 0);
  }
  float bgv = bg[lo];
#pragma unroll
  for (int r = 0; r < 4; ++r) {
    float x = acc[r] + bgv;
    G[(size_t)(m0 + 4*hi + r) * NH + lo] = 1.f / (1.f + __builtin_amdgcn_exp2f(-x * LOG2E));
  }
}

// ---------------- flash attention v8: 256 threads / 4 waves, QBLK=128, 2 blocks/CU -----
// v6's verified per-fragment schedule; wave owns 32 q-rows (2 frags of 16). K,V both
// double-buffered + private pbuf = 72 KB LDS (2 blocks x 72 = 144 <= 160). 256-thread
// blocks co-schedule 2/CU (r13 GEMM evidence) -> cross-block overlap of barrier stalls.
__global__ __launch_bounds__(256) void attn_kernel(const unsigned short* __restrict__ Q,
                                                   const unsigned short* __restrict__ Kb,
                                                   const unsigned short* __restrict__ VT,
                                                   const unsigned short* __restrict__ biasb,
                                                   const float* __restrict__ G,
                                                   unsigned short* __restrict__ OG) {
  __shared__ __align__(16) unsigned short kbuf[2][64*128];   // 32 KB, [key][d] swz rows
  __shared__ __align__(16) unsigned short vbuf[2][128*64];   // 32 KB, [d][key] swz rows
  __shared__ __align__(16) unsigned short pbuf[4*16*64];     // 8 KB, per-wave P

  int bid = blockIdx.x;
  int h  = bid & 15;
  int b  = (bid >> 4) & 1;
  int qt = bid >> 5;                      // 0..15
  int bh = b*NH + h;

  int tid = threadIdx.x, wid = tid >> 6, lane = tid & 63;
  int lo = lane & 15, hi = lane >> 4;
  int qw0 = qt*128 + wid*32;

  float hs2 = __builtin_amdgcn_exp2f(-(float)(h+1) * 0.5f) * LOG2E;

  short8 qf[2][4];
#pragma unroll
  for (int f2 = 0; f2 < 2; ++f2)
#pragma unroll
    for (int ks = 0; ks < 4; ++ks)
      qf[f2][ks] = *(const short8*)&Q[((size_t)bh*SEQ + qw0 + f2*16 + lo)*DK + ks*32 + hi*8];

  f32x4 zero4 = {0.f,0.f,0.f,0.f};
  f32x4 acco[2][8];
#pragma unroll
  for (int f2 = 0; f2 < 2; ++f2)
#pragma unroll
    for (int f = 0; f < 8; ++f) acco[f2][f] = zero4;
  float lrun[2][4];
#pragma unroll
  for (int f2 = 0; f2 < 2; ++f2)
#pragma unroll
    for (int r = 0; r < 4; ++r) lrun[f2][r] = 0.f;

  const char* kbase = (const char*)Kb + ((size_t)bh*SEQ)*DK*2;
  const char* vbase = (const char*)VT + ((size_t)bh*DK)*SEQ*2;
  const unsigned short* bb = biasb + ((size_t)b*SEQ + qw0 + 4*hi)*SEQ + lo;
  char* pb = (char*)pbuf + wid*2048;

  int s16 = lane >> 4, srow8 = lane >> 3;
  int kof = (lane & 15) * 16, vof = (lane & 7) * 16;

  // 8 gl_lds16/thread/tile: 4 K-chunks + 4 V-chunks (256 threads cover 16KB each)
#define STAGE_KV(KT, BUF) do {                                                        \
    _Pragma("unroll")                                                                 \
    for (int c = 0; c < 4; ++c) {                                                     \
      int ch = wid*4 + c;                                                             \
      int krc = ch*4 + s16;                                                           \
      gl_lds16(kbase + (size_t)((KT) + krc)*256 + (kof ^ ((krc & 7) << 4)),           \
               (char*)kbuf[BUF] + ch*1024);                                           \
      int vrc = ch*8 + srow8;                                                         \
      gl_lds16(vbase + (size_t)vrc*4096 + (size_t)(KT)*2 + (vof ^ (srow8 << 4)),      \
               (char*)vbuf[BUF] + ch*1024);                                           \
    }                                                                                 \
  } while(0)

  unsigned short br[2][4][4];
#pragma unroll
  for (int f2 = 0; f2 < 2; ++f2)
#pragma unroll
    for (int r = 0; r < 4; ++r)
#pragma unroll
      for (int nf = 0; nf < 4; ++nf)
        br[f2][r][nf] = bb[(size_t)(f2*16 + r)*SEQ + nf*16];
  STAGE_KV(0, 0);
  STAGE_KV(64, 1);
  asm volatile("s_waitcnt vmcnt(8)" ::: "memory");   // bias(0)+KV(0) landed, KV(64) in flight
  SBAR();

  const int NT = SEQ / 64;
  int cur = 0;
  for (int t = 0; t < NT; ++t) {
#pragma unroll
    for (int f2 = 0; f2 < 2; ++f2) {
      // ---- QK^T fragment f2 from kbuf[cur] ----
      f32x4 sf[4];
      __builtin_amdgcn_s_setprio(1);
#pragma unroll
      for (int nf = 0; nf < 4; ++nf) {
        f32x4 a = zero4;
#pragma unroll
        for (int ks = 0; ks < 4; ++ks) {
          int krw = nf*16 + lo;
          int cb = (ks*32 + hi*8)*2;
          short8 kf = *(const short8*)((const char*)kbuf[cur] + krw*256 + (cb ^ ((krw & 7) << 4)));
          a = __builtin_amdgcn_mfma_f32_16x16x32_bf16(qf[f2][ks], kf, a, 0, 0, 0);
        }
        sf[nf] = a;
      }
      __builtin_amdgcn_s_setprio(0);

      // ---- direct exp2 softmax (no max), P into per-wave pbuf (reused per frag) ----
#pragma unroll
      for (int r = 0; r < 4; ++r) {
        int prow = 4*hi + r;
#pragma unroll
        for (int nf = 0; nf < 4; ++nf) {
          float s = fmaf(b2f(br[f2][r][nf]), hs2, sf[nf][r]);
          float p = __builtin_amdgcn_exp2f(s);
          lrun[f2][r] += p;
          *(unsigned short*)(pb + prow*128 + ((((nf*16 + lo)*2)) ^ ((prow & 7) << 4))) = f2b(p);
        }
      }

      // ---- PV fragment f2 from vbuf[cur] ----
      short8 pf[2];
#pragma unroll
      for (int ks = 0; ks < 2; ++ks)
        pf[ks] = *(const short8*)(pb + lo*128 + ((ks*64 + hi*16) ^ ((lo & 7) << 4)));
      __builtin_amdgcn_s_setprio(1);
#pragma unroll
      for (int f = 0; f < 8; ++f) {
#pragma unroll
        for (int ks = 0; ks < 2; ++ks) {
          int vrw = f*16 + lo;
          int cb = (ks*32 + hi*8)*2;
          short8 vf = *(const short8*)((const char*)vbuf[cur] + vrw*128 + (cb ^ ((vrw & 7) << 4)));
          acco[f2][f] = __builtin_amdgcn_mfma_f32_16x16x32_bf16(pf[ks], vf, acco[f2][f], 0, 0, 0);
        }
      }
      __builtin_amdgcn_s_setprio(0);
    }

    LGKM0(); SBAR();                    // B2: all waves done reading kbuf/vbuf[cur]

    bool more1 = (t + 1) < NT;
    bool more2 = (t + 2) < NT;
    if (more1) {                         // bias(t+1): issued BEFORE next K/V stage (older)
      int ktn = (t + 1) * 64;
#pragma unroll
      for (int f2 = 0; f2 < 2; ++f2)
#pragma unroll
        for (int r = 0; r < 4; ++r)
#pragma unroll
          for (int nf = 0; nf < 4; ++nf)
            br[f2][r][nf] = bb[(size_t)(f2*16 + r)*SEQ + ktn + nf*16];
    }
    if (more2) {
      STAGE_KV((t + 2) * 64, cur);
      asm volatile("s_waitcnt vmcnt(40)" ::: "memory");  // KV(t+1) landed; 32 bias + 8 KV fly
    } else if (more1) {
      asm volatile("s_waitcnt vmcnt(32)" ::: "memory");  // KV(t+1) landed; 32 bias fly
    }
    SBAR();                             // B3: tile t+1 visible to all waves
    cur ^= 1;
  }
#undef STAGE_KV

  // ---- final l reduction over lo-lanes (once) ----
#pragma unroll
  for (int f2 = 0; f2 < 2; ++f2)
#pragma unroll
    for (int r = 0; r < 4; ++r) {
      float l = lrun[f2][r];
      l += __shfl_xor(l, 1); l += __shfl_xor(l, 2);
      l += __shfl_xor(l, 4); l += __shfl_xor(l, 8);
      lrun[f2][r] = l;
    }

  // ---- epilogue: normalize, gate, write OG[b,s, h*128+d] bf16 ----
#pragma unroll
  for (int f2 = 0; f2 < 2; ++f2)
#pragma unroll
    for (int r = 0; r < 4; ++r) {
      int qrow = qw0 + f2*16 + 4*hi + r;
      float inv = 1.f / lrun[f2][r];
      float g = G[((size_t)(b*SEQ + qrow))*NH + h];
      float sgl = inv * g;
#pragma unroll
      for (int f = 0; f < 8; ++f)
        OG[((size_t)(b*SEQ) + qrow)*DM + h*DK + f*16 + lo] = f2b(acco[f2][f][r] * sgl);
    }
}

// ---------------- launcher ----------------
extern "C" void kernel_launch(void* const* d_in, const int* in_sizes, int n_in,
                              void* d_out, int out_size, void* d_ws, size_t ws_size,
                              hipStream_t stream) {
  const float* states    = (const float*)d_in[0];
  const float* bias_mask = (const float*)d_in[1];
  const float* wq = (const float*)d_in[2];
  const float* bq = (const float*)d_in[3];
  const float* wk = (const float*)d_in[4];
  const float* bk = (const float*)d_in[5];
  const float* wv = (const float*)d_in[6];
  const float* bv = (const float*)d_in[7];
  const float* wg = (const float*)d_in[8];
  const float* bg = (const float*)d_in[9];
  const float* wo = (const float*)d_in[10];
  const float* bo = (const float*)d_in[11];

  char* ws = (char*)d_ws;
  unsigned short* XB   = (unsigned short*)(ws + 0);              // aliased by OGB later
  unsigned short* OGB  = XB;
  unsigned short* WQVT = (unsigned short*)(ws + 16777216UL);     // 4 x 8.39MB contiguous (Q,K,V,O)
  unsigned short* WOT  = (unsigned short*)(ws + 41943040UL);
  unsigned short* QB   = (unsigned short*)(ws + 50331648UL);
  unsigned short* KB   = (unsigned short*)(ws + 67108864UL);
  unsigned short* VTB  = (unsigned short*)(ws + 83886080UL);
  unsigned short* BIASB= (unsigned short*)(ws + 100663296UL);
  float*          GB   = (float*)         (ws + 117440512UL);
  unsigned short* WGT  = (unsigned short*)(ws + 117702656UL);    // 64 KB

  cast2_bf16_kernel<<<8192, 256, 0, stream>>>(states, XB, bias_mask, BIASB);
  transpose_cast4_kernel<<<dim3(32, 32, 4), 256, 0, stream>>>(wq, wk, wv, wo, WQVT);
  transpose_wg_kernel<<<32, 256, 0, stream>>>(wg, WGT);

  gemm128_qkv_kernel<<<dim3(48, 32), 256, 0, stream>>>(XB, WQVT, bq, bk, bv, QB, KB, VTB);

  gate_mfma_kernel<<<64, 256, 0, stream>>>(XB, WGT, bg, GB);

  attn_kernel<<<512, 256, 0, stream>>>(QB, KB, VTB, BIASB, GB, OGB);

  gemm128_ao_kernel<<<dim3(16, 32), 256, 0, stream>>>(OGB, WOT, bo, (float*)d_out);
}

// Round 16
// 379.187 us; speedup vs baseline: 1.0117x; 1.0117x over previous
//
#include <hip/hip_runtime.h>
#include <hip/hip_bf16.h>

#define SEQ 2048
#define DM 2048
#define NH 16
#define DK 128
#define LOG2E 1.4426950408889634f
#define QK_SCALE 0.08838834764831845f   // 128^-0.5

typedef __attribute__((ext_vector_type(8))) short short8;
typedef __attribute__((ext_vector_type(4))) float f32x4;
typedef __attribute__((ext_vector_type(4))) unsigned short us4;

__device__ __forceinline__ unsigned short f2b(float f) {
  union { float f; unsigned u; } v; v.f = f;
  unsigned r = v.u + 0x7fffu + ((v.u >> 16) & 1u);
  return (unsigned short)(r >> 16);
}
__device__ __forceinline__ float b2f(unsigned short v) {
  union { unsigned u; float f; } x; x.u = ((unsigned)v) << 16; return x.f;
}

__device__ __forceinline__ void gl_lds16(const void* g, void* l) {
  __builtin_amdgcn_global_load_lds((const __attribute__((address_space(1))) void*)g,
                                   (__attribute__((address_space(3))) void*)l, 16, 0, 0);
}

#define SBAR()   __builtin_amdgcn_s_barrier()
#define SCHED0() __builtin_amdgcn_sched_barrier(0)
#define LGKM0()  asm volatile("s_waitcnt lgkmcnt(0)" ::: "memory")

// ---------------- fused cast f32 -> bf16: states (4096 blk) + bias (4096 blk) ----------
__global__ __launch_bounds__(256) void cast2_bf16_kernel(const float* __restrict__ in0,
                                                         unsigned short* __restrict__ out0,
                                                         const float* __restrict__ in1,
                                                         unsigned short* __restrict__ out1) {
  int bid = blockIdx.x;
  const float* in = (bid < 4096) ? in0 : in1;
  unsigned short* out = (bid < 4096) ? out0 : out1;
  int i = ((bid < 4096) ? bid : bid - 4096) * 256 + threadIdx.x;
  const float4* p = (const float4*)in;
  float4 a = p[2*i], b = p[2*i+1];
  us4 r0, r1;
  r0[0]=f2b(a.x); r0[1]=f2b(a.y); r0[2]=f2b(a.z); r0[3]=f2b(a.w);
  r1[0]=f2b(b.x); r1[1]=f2b(b.y); r1[2]=f2b(b.z); r1[3]=f2b(b.w);
  us4* o = (us4*)out;
  o[2*i] = r0; o[2*i+1] = r1;
}

// ---------------- fused transpose+cast: 4 x w[2048][2048] f32 -> wt = w^T bf16 ----------
__global__ __launch_bounds__(256) void transpose_cast4_kernel(const float* __restrict__ w0,
                                                              const float* __restrict__ w1,
                                                              const float* __restrict__ w2,
                                                              const float* __restrict__ w3,
                                                              unsigned short* __restrict__ dst) {
  const float* w = (blockIdx.z == 0) ? w0 : (blockIdx.z == 1) ? w1 : (blockIdx.z == 2) ? w2 : w3;
  unsigned short* wt = dst + (size_t)blockIdx.z * DM * DM;
  __shared__ float t[64][65];
  int c0 = blockIdx.x * 64, r0 = blockIdx.y * 64;
  int tid = threadIdx.x;
  int rr = tid >> 4;
  int c4 = (tid & 15) * 4;
#pragma unroll
  for (int p = 0; p < 4; ++p) {
    int r = p*16 + rr;
    float4 v = *(const float4*)&w[(size_t)(r0 + r)*DM + c0 + c4];
    t[r][c4] = v.x; t[r][c4+1] = v.y; t[r][c4+2] = v.z; t[r][c4+3] = v.w;
  }
  __syncthreads();
#pragma unroll
  for (int p = 0; p < 4; ++p) {
    int c = p*16 + rr;
    us4 v;
    v[0] = f2b(t[c4+0][c]); v[1] = f2b(t[c4+1][c]);
    v[2] = f2b(t[c4+2][c]); v[3] = f2b(t[c4+3][c]);
    *(us4*)&wt[(size_t)(c0 + c)*DM + r0 + c4] = v;
  }
}

// ---------------- transpose + cast wg[2048][16] f32 -> wgT[16][2048] bf16 ----------------
__global__ __launch_bounds__(256) void transpose_wg_kernel(const float* __restrict__ wg,
                                                           unsigned short* __restrict__ wgT) {
  int idx = blockIdx.x * 256 + threadIdx.x;
  int c = idx & 15;
  int r0 = (idx >> 4) * 4;
#pragma unroll
  for (int r = 0; r < 4; ++r)
    wgT[(size_t)c*DM + r0 + r] = f2b(wg[(size_t)(r0 + r)*NH + c]);
}

// ================= 128x128 / BK=64 / 4-wave / 2-phase GEMM core — 2 blocks/CU ===========
__device__ __forceinline__ void gemm128x128_core(const unsigned short* __restrict__ A,
                                                 const unsigned short* __restrict__ Bt,
                                                 int m0, int n0, f32x4 (&acc)[4][4]) {
  __shared__ __align__(16) unsigned short Ab[2][8192];
  __shared__ __align__(16) unsigned short Bb[2][8192];
  const int TK = DM / 64;   // 32 K-steps

  int tid = threadIdx.x, wid = tid >> 6, lane = tid & 63;
  int lo = lane & 15, hi = lane >> 4;
  int wm = wid >> 1, wn = wid & 1;

  int srow8 = lane >> 3;
  int skb = (((lane & 7) ^ srow8) << 4);
  const char* Ag = (const char*)A;
  const char* Bg = (const char*)Bt;

#define STG_A(S,CUR) do {                                                          \
    const char* g = Ag + (size_t)(S)*128 + skb;                                    \
    char* l = (char*)&Ab[CUR][0] + wid*4096;                                       \
    _Pragma("unroll")                                                              \
    for (int c = 0; c < 4; ++c)                                                    \
      gl_lds16(g + (size_t)(m0 + wid*32 + c*8 + srow8)*4096, l + c*1024);          \
  } while(0)
#define STG_B(S,CUR) do {                                                          \
    const char* g = Bg + (size_t)(S)*128 + skb;                                    \
    char* l = (char*)&Bb[CUR][0] + wid*4096;                                       \
    _Pragma("unroll")                                                              \
    for (int c = 0; c < 4; ++c)                                                    \
      gl_lds16(g + (size_t)(n0 + wid*32 + c*8 + srow8)*4096, l + c*1024);          \
  } while(0)

#pragma unroll
  for (int i = 0; i < 4; ++i)
#pragma unroll
    for (int j = 0; j < 4; ++j) acc[i][j] = (f32x4){0.f,0.f,0.f,0.f};

  STG_B(0,0); STG_A(0,0); STG_B(1,1); STG_A(1,1);
  asm volatile("s_waitcnt vmcnt(8)" ::: "memory");
  SBAR();

  int msk = (lo & 7) << 4;
  int k0 = (hi*16) ^ msk;
  int k1 = (64 + hi*16) ^ msk;

  short8 a[4][2], bA[2][2], bB[2][2];

#define MF16(NHH,BF)                                                                \
  __builtin_amdgcn_s_setprio(1);                                                    \
  _Pragma("unroll") for (int mi = 0; mi < 4; ++mi)                                  \
  _Pragma("unroll") for (int nn = 0; nn < 2; ++nn) {                                \
    acc[mi][(NHH)*2+nn] = __builtin_amdgcn_mfma_f32_16x16x32_bf16(                  \
        a[mi][0], BF[nn][0], acc[mi][(NHH)*2+nn], 0, 0, 0);                         \
    acc[mi][(NHH)*2+nn] = __builtin_amdgcn_mfma_f32_16x16x32_bf16(                  \
        a[mi][1], BF[nn][1], acc[mi][(NHH)*2+nn], 0, 0, 0);                         \
  }                                                                                 \
  __builtin_amdgcn_s_setprio(0);

  for (int s = 0; s < TK; ++s) {
    int cur = s & 1;
    const char* Ac = (const char*)&Ab[cur][0];
    const char* Bc = (const char*)&Bb[cur][0];
    bool pre = (s + 2) < TK;

#pragma unroll
    for (int mm = 0; mm < 4; ++mm) {
      a[mm][0] = *(const short8*)(Ac + (wm*64 + mm*16 + lo)*128 + k0);
      a[mm][1] = *(const short8*)(Ac + (wm*64 + mm*16 + lo)*128 + k1);
    }
#pragma unroll
    for (int nn = 0; nn < 2; ++nn) {
      bA[nn][0] = *(const short8*)(Bc + (wn*64 + nn*16 + lo)*128 + k0);
      bA[nn][1] = *(const short8*)(Bc + (wn*64 + nn*16 + lo)*128 + k1);
      bB[nn][0] = *(const short8*)(Bc + (wn*64 + (2+nn)*16 + lo)*128 + k0);
      bB[nn][1] = *(const short8*)(Bc + (wn*64 + (2+nn)*16 + lo)*128 + k1);
    }
    SBAR(); LGKM0(); SCHED0();
    MF16(0, bA);
    SBAR();

    if (pre) {
      STG_B(s + 2, cur);
      STG_A(s + 2, cur);
      asm volatile("s_waitcnt vmcnt(8)" ::: "memory");
    } else if (s == TK - 2) {
      asm volatile("s_waitcnt vmcnt(0)" ::: "memory");
    }
    SBAR();
    MF16(1, bB);
    SBAR();
  }
#undef STG_A
#undef STG_B
#undef MF16
}

// ---------------- fused QKV GEMM: A(4096x2048) x WQVT(6144x2048)^T, grid 48x32 --------
__global__ __launch_bounds__(256, 2) void gemm128_qkv_kernel(const unsigned short* __restrict__ A,
                                                             const unsigned short* __restrict__ Bt,
                                                             const float* __restrict__ bq,
                                                             const float* __restrict__ bk,
                                                             const float* __restrict__ bv,
                                                             unsigned short* __restrict__ QB,
                                                             unsigned short* __restrict__ KB,
                                                             unsigned short* __restrict__ VTB) {
  f32x4 acc[4][4];
  int n0 = blockIdx.x * 128, m0 = blockIdx.y * 128;
  gemm128x128_core(A, Bt, m0, n0, acc);

  int tid = threadIdx.x, wid = tid >> 6, lane = tid & 63;
  int lo = lane & 15, hi = lane >> 4;
  int wm = wid >> 1, wn = wid & 1;
  int m_base = m0 + wm*64;
  int n_base = n0 + wn*64;
  int sect = n0 >> 11;

  if (sect == 2) {       // V -> transposed [b,h,d,s]
#pragma unroll
    for (int mi = 0; mi < 4; ++mi) {
      int m = m_base + mi*16 + 4*hi;
      int b = m >> 11, srow = m & 2047;
#pragma unroll
      for (int nf = 0; nf < 4; ++nf) {
        int n = n_base + nf*16 + lo;
        int nl = n & 2047, h = nl >> 7, d = nl & 127;
        float bvv = bv[nl];
        us4 pk;
#pragma unroll
        for (int r = 0; r < 4; ++r) pk[r] = f2b(acc[mi][nf][r] + bvv);
        *(us4*)&VTB[(((size_t)(b*NH + h))*DK + d)*SEQ + srow] = pk;
      }
    }
  } else {
    unsigned short* out = sect ? KB : QB;
    const float* bp = sect ? bk : bq;
    const float qs = sect ? 1.f : QK_SCALE * LOG2E;
#pragma unroll
    for (int mi = 0; mi < 4; ++mi) {
#pragma unroll
      for (int nf = 0; nf < 4; ++nf) {
        int n = n_base + nf*16 + lo;
        int nl = n & 2047, h = nl >> 7, d = nl & 127;
        float bvv = bp[nl];
#pragma unroll
        for (int r = 0; r < 4; ++r) {
          int m = m_base + mi*16 + 4*hi + r;
          int b = m >> 11, srow = m & 2047;
          out[(((size_t)(b*NH + h))*SEQ + srow)*DK + d] = f2b((acc[mi][nf][r] + bvv) * qs);
        }
      }
    }
  }
}

// ---------------- AO GEMM: grid 16x32 = 512 blocks = 1 full round at 2/CU --------------
__global__ __launch_bounds__(256, 2) void gemm128_ao_kernel(const unsigned short* __restrict__ A,
                                                            const unsigned short* __restrict__ Bt,
                                                            const float* __restrict__ bias,
                                                            float* __restrict__ out) {
  f32x4 acc[4][4];
  int n0 = blockIdx.x * 128, m0 = blockIdx.y * 128;
  gemm128x128_core(A, Bt, m0, n0, acc);

  int tid = threadIdx.x, wid = tid >> 6, lane = tid & 63;
  int lo = lane & 15, hi = lane >> 4;
  int wm = wid >> 1, wn = wid & 1;
#pragma unroll
  for (int mi = 0; mi < 4; ++mi) {
#pragma unroll
    for (int nf = 0; nf < 4; ++nf) {
      int n = n0 + wn*64 + nf*16 + lo;
      float bvv = bias[n];
#pragma unroll
      for (int r = 0; r < 4; ++r) {
        int m = m0 + wm*64 + mi*16 + 4*hi + r;
        out[(size_t)m*DM + n] = acc[mi][nf][r] + bvv;
      }
    }
  }
}

// ---------------- gate via MFMA: G[m][h] = sigmoid(XB[m]·wgT[h] + bg[h]) ----------------
__global__ __launch_bounds__(256) void gate_mfma_kernel(const unsigned short* __restrict__ XB,
                                                        const unsigned short* __restrict__ wgT,
                                                        const float* __restrict__ bg,
                                                        float* __restrict__ G) {
  int tid = threadIdx.x, wid = tid >> 6, lane = tid & 63;
  int lo = lane & 15, hi = lane >> 4;
  int m0 = blockIdx.x * 64 + wid * 16;

  f32x4 acc = {0.f, 0.f, 0.f, 0.f};
  const unsigned short* xrow = XB + (size_t)(m0 + lo) * DM + hi * 8;
  const unsigned short* grow = wgT + (size_t)lo * DM + hi * 8;
#pragma unroll 4
  for (int kt = 0; kt < DM; kt += 32) {
    short8 a = *(const short8*)(xrow + kt);
    short8 b = *(const short8*)(grow + kt);
    acc = __builtin_amdgcn_mfma_f32_16x16x32_bf16(a, b, acc, 0, 0, 0);
  }
  float bgv = bg[lo];
#pragma unroll
  for (int r = 0; r < 4; ++r) {
    float x = acc[r] + bgv;
    G[(size_t)(m0 + 4*hi + r) * NH + lo] = 1.f / (1.f + __builtin_amdgcn_exp2f(-x * LOG2E));
  }
}

// ---------------- flash attention v9: 256 thr / 4 waves, 64 KB LDS -> 2 blocks/CU -------
// v8's schedule with P overlaying kbuf[cur] (no pbuf): both fragments' QK^T complete
// before B1, then P may overwrite kbuf[cur]. Per-wave-per-frag 2 KB P slots (4 waves x
// 2 frags x 2KB = 16KB = kbuf[cur]). 3 barriers/tile; staging/vmcnt identical to v8.
__global__ __launch_bounds__(256) void attn_kernel(const unsigned short* __restrict__ Q,
                                                   const unsigned short* __restrict__ Kb,
                                                   const unsigned short* __restrict__ VT,
                                                   const unsigned short* __restrict__ biasb,
                                                   const float* __restrict__ G,
                                                   unsigned short* __restrict__ OG) {
  __shared__ __align__(16) unsigned short kbuf[2][64*128];   // 32 KB, [key][d] swz rows
  __shared__ __align__(16) unsigned short vbuf[2][128*64];   // 32 KB, [d][key] swz rows

  int bid = blockIdx.x;
  int h  = bid & 15;
  int b  = (bid >> 4) & 1;
  int qt = bid >> 5;                      // 0..15
  int bh = b*NH + h;

  int tid = threadIdx.x, wid = tid >> 6, lane = tid & 63;
  int lo = lane & 15, hi = lane >> 4;
  int qw0 = qt*128 + wid*32;

  float hs2 = __builtin_amdgcn_exp2f(-(float)(h+1) * 0.5f) * LOG2E;

  short8 qf[2][4];
#pragma unroll
  for (int f2 = 0; f2 < 2; ++f2)
#pragma unroll
    for (int ks = 0; ks < 4; ++ks)
      qf[f2][ks] = *(const short8*)&Q[((size_t)bh*SEQ + qw0 + f2*16 + lo)*DK + ks*32 + hi*8];

  f32x4 zero4 = {0.f,0.f,0.f,0.f};
  f32x4 acco[2][8];
#pragma unroll
  for (int f2 = 0; f2 < 2; ++f2)
#pragma unroll
    for (int f = 0; f < 8; ++f) acco[f2][f] = zero4;
  float lrun[2][4];
#pragma unroll
  for (int f2 = 0; f2 < 2; ++f2)
#pragma unroll
    for (int r = 0; r < 4; ++r) lrun[f2][r] = 0.f;

  const char* kbase = (const char*)Kb + ((size_t)bh*SEQ)*DK*2;
  const char* vbase = (const char*)VT + ((size_t)bh*DK)*SEQ*2;
  const unsigned short* bb = biasb + ((size_t)b*SEQ + qw0 + 4*hi)*SEQ + lo;

  int s16 = lane >> 4, srow8 = lane >> 3;
  int kof = (lane & 15) * 16, vof = (lane & 7) * 16;

  // 8 gl_lds16/thread/tile: 4 K-chunks + 4 V-chunks (256 threads cover 16KB each)
#define STAGE_KV(KT, BUF) do {                                                        \
    _Pragma("unroll")                                                                 \
    for (int c = 0; c < 4; ++c) {                                                     \
      int ch = wid*4 + c;                                                             \
      int krc = ch*4 + s16;                                                           \
      gl_lds16(kbase + (size_t)((KT) + krc)*256 + (kof ^ ((krc & 7) << 4)),           \
               (char*)kbuf[BUF] + ch*1024);                                           \
      int vrc = ch*8 + srow8;                                                         \
      gl_lds16(vbase + (size_t)vrc*4096 + (size_t)(KT)*2 + (vof ^ (srow8 << 4)),      \
               (char*)vbuf[BUF] + ch*1024);                                           \
    }                                                                                 \
  } while(0)

  unsigned short br[2][4][4];
#pragma unroll
  for (int f2 = 0; f2 < 2; ++f2)
#pragma unroll
    for (int r = 0; r < 4; ++r)
#pragma unroll
      for (int nf = 0; nf < 4; ++nf)
        br[f2][r][nf] = bb[(size_t)(f2*16 + r)*SEQ + nf*16];
  STAGE_KV(0, 0);
  STAGE_KV(64, 1);
  asm volatile("s_waitcnt vmcnt(8)" ::: "memory");   // bias(0)+KV(0) landed, KV(64) in flight
  SBAR();

  const int NT = SEQ / 64;
  int cur = 0;
  for (int t = 0; t < NT; ++t) {
    // ---- QK^T for BOTH fragments from kbuf[cur] (must finish before P overlay) ----
    f32x4 sf[2][4];
    __builtin_amdgcn_s_setprio(1);
#pragma unroll
    for (int f2 = 0; f2 < 2; ++f2)
#pragma unroll
      for (int nf = 0; nf < 4; ++nf) {
        f32x4 a = zero4;
#pragma unroll
        for (int ks = 0; ks < 4; ++ks) {
          int krw = nf*16 + lo;
          int cb = (ks*32 + hi*8)*2;
          short8 kf = *(const short8*)((const char*)kbuf[cur] + krw*256 + (cb ^ ((krw & 7) << 4)));
          a = __builtin_amdgcn_mfma_f32_16x16x32_bf16(qf[f2][ks], kf, a, 0, 0, 0);
        }
        sf[f2][nf] = a;
      }
    __builtin_amdgcn_s_setprio(0);

    LGKM0(); SBAR();                    // B1: all waves' QK reads done -> P may overlay kbuf[cur]
    char* pbase = (char*)kbuf[cur] + wid*4096;

#pragma unroll
    for (int f2 = 0; f2 < 2; ++f2) {
      char* pb = pbase + f2*2048;
      // ---- direct exp2 softmax (no max), P into kbuf[cur] overlay slot ----
#pragma unroll
      for (int r = 0; r < 4; ++r) {
        int prow = 4*hi + r;
#pragma unroll
        for (int nf = 0; nf < 4; ++nf) {
          float s = fmaf(b2f(br[f2][r][nf]), hs2, sf[f2][nf][r]);
          float p = __builtin_amdgcn_exp2f(s);
          lrun[f2][r] += p;
          *(unsigned short*)(pb + prow*128 + ((((nf*16 + lo)*2)) ^ ((prow & 7) << 4))) = f2b(p);
        }
      }

      // ---- PV fragment f2 from vbuf[cur] ----
      short8 pf[2];
#pragma unroll
      for (int ks = 0; ks < 2; ++ks)
        pf[ks] = *(const short8*)(pb + lo*128 + ((ks*64 + hi*16) ^ ((lo & 7) << 4)));
      __builtin_amdgcn_s_setprio(1);
#pragma unroll
      for (int f = 0; f < 8; ++f) {
#pragma unroll
        for (int ks = 0; ks < 2; ++ks) {
          int vrw = f*16 + lo;
          int cb = (ks*32 + hi*8)*2;
          short8 vf = *(const short8*)((const char*)vbuf[cur] + vrw*128 + (cb ^ ((vrw & 7) << 4)));
          acco[f2][f] = __builtin_amdgcn_mfma_f32_16x16x32_bf16(pf[ks], vf, acco[f2][f], 0, 0, 0);
        }
      }
      __builtin_amdgcn_s_setprio(0);
    }

    LGKM0(); SBAR();                    // B2: P + vbuf[cur] reads done -> restage kbuf[cur] ok

    bool more1 = (t + 1) < NT;
    bool more2 = (t + 2) < NT;
    if (more1) {                         // bias(t+1): issued BEFORE next K/V stage (older)
      int ktn = (t + 1) * 64;
#pragma unroll
      for (int f2 = 0; f2 < 2; ++f2)
#pragma unroll
        for (int r = 0; r < 4; ++r)
#pragma unroll
          for (int nf = 0; nf < 4; ++nf)
            br[f2][r][nf] = bb[(size_t)(f2*16 + r)*SEQ + ktn + nf*16];
    }
    if (more2) {
      STAGE_KV((t + 2) * 64, cur);
      asm volatile("s_waitcnt vmcnt(40)" ::: "memory");  // KV(t+1) landed; 32 bias + 8 KV fly
    } else if (more1) {
      asm volatile("s_waitcnt vmcnt(32)" ::: "memory");  // KV(t+1) landed; 32 bias fly
    }
    SBAR();                             // B3: tile t+1 visible to all waves
    cur ^= 1;
  }
#undef STAGE_KV

  // ---- final l reduction over lo-lanes (once) ----
#pragma unroll
  for (int f2 = 0; f2 < 2; ++f2)
#pragma unroll
    for (int r = 0; r < 4; ++r) {
      float l = lrun[f2][r];
      l += __shfl_xor(l, 1); l += __shfl_xor(l, 2);
      l += __shfl_xor(l, 4); l += __shfl_xor(l, 8);
      lrun[f2][r] = l;
    }

  // ---- epilogue: normalize, gate, write OG[b,s, h*128+d] bf16 ----
#pragma unroll
  for (int f2 = 0; f2 < 2; ++f2)
#pragma unroll
    for (int r = 0; r < 4; ++r) {
      int qrow = qw0 + f2*16 + 4*hi + r;
      float inv = 1.f / lrun[f2][r];
      float g = G[((size_t)(b*SEQ + qrow))*NH + h];
      float sgl = inv * g;
#pragma unroll
      for (int f = 0; f < 8; ++f)
        OG[((size_t)(b*SEQ) + qrow)*DM + h*DK + f*16 + lo] = f2b(acco[f2][f][r] * sgl);
    }
}

// ---------------- launcher ----------------
extern "C" void kernel_launch(void* const* d_in, const int* in_sizes, int n_in,
                              void* d_out, int out_size, void* d_ws, size_t ws_size,
                              hipStream_t stream) {
  const float* states    = (const float*)d_in[0];
  const float* bias_mask = (const float*)d_in[1];
  const float* wq = (const float*)d_in[2];
  const float* bq = (const float*)d_in[3];
  const float* wk = (const float*)d_in[4];
  const float* bk = (const float*)d_in[5];
  const float* wv = (const float*)d_in[6];
  const float* bv = (const float*)d_in[7];
  const float* wg = (const float*)d_in[8];
  const float* bg = (const float*)d_in[9];
  const float* wo = (const float*)d_in[10];
  const float* bo = (const float*)d_in[11];

  char* ws = (char*)d_ws;
  unsigned short* XB   = (unsigned short*)(ws + 0);              // aliased by OGB later
  unsigned short* OGB  = XB;
  unsigned short* WQVT = (unsigned short*)(ws + 16777216UL);     // 4 x 8.39MB contiguous (Q,K,V,O)
  unsigned short* WOT  = (unsigned short*)(ws + 41943040UL);
  unsigned short* QB   = (unsigned short*)(ws + 50331648UL);
  unsigned short* KB   = (unsigned short*)(ws + 67108864UL);
  unsigned short* VTB  = (unsigned short*)(ws + 83886080UL);
  unsigned short* BIASB= (unsigned short*)(ws + 100663296UL);
  float*          GB   = (float*)         (ws + 117440512UL);
  unsigned short* WGT  = (unsigned short*)(ws + 117702656UL);    // 64 KB

  cast2_bf16_kernel<<<8192, 256, 0, stream>>>(states, XB, bias_mask, BIASB);
  transpose_cast4_kernel<<<dim3(32, 32, 4), 256, 0, stream>>>(wq, wk, wv, wo, WQVT);
  transpose_wg_kernel<<<32, 256, 0, stream>>>(wg, WGT);

  gemm128_qkv_kernel<<<dim3(48, 32), 256, 0, stream>>>(XB, WQVT, bq, bk, bv, QB, KB, VTB);

  gate_mfma_kernel<<<64, 256, 0, stream>>>(XB, WGT, bg, GB);

  attn_kernel<<<512, 256, 0, stream>>>(QB, KB, VTB, BIASB, GB, OGB);

  gemm128_ao_kernel<<<dim3(16, 32), 256, 0, stream>>>(OGB, WOT, bo, (float*)d_out);
}

// Round 17
// 322.464 us; speedup vs baseline: 1.1897x; 1.1759x over previous
//
#include <hip/hip_runtime.h>
#include <hip/hip_bf16.h>

#define SEQ 2048
#define DM 2048
#define NH 16
#define DK 128
#define LOG2E 1.4426950408889634f
#define QK_SCALE 0.08838834764831845f   // 128^-0.5

typedef __attribute__((ext_vector_type(8))) short short8;
typedef __attribute__((ext_vector_type(4))) float f32x4;
typedef __attribute__((ext_vector_type(4))) unsigned short us4;

__device__ __forceinline__ unsigned short f2b(float f) {
  union { float f; unsigned u; } v; v.f = f;
  unsigned r = v.u + 0x7fffu + ((v.u >> 16) & 1u);
  return (unsigned short)(r >> 16);
}
__device__ __forceinline__ float b2f(unsigned short v) {
  union { unsigned u; float f; } x; x.u = ((unsigned)v) << 16; return x.f;
}

__device__ __forceinline__ void gl_lds16(const void* g, void* l) {
  __builtin_amdgcn_global_load_lds((const __attribute__((address_space(1))) void*)g,
                                   (__attribute__((address_space(3))) void*)l, 16, 0, 0);
}

#define SBAR()   __builtin_amdgcn_s_barrier()
#define SCHED0() __builtin_amdgcn_sched_barrier(0)
#define LGKM0()  asm volatile("s_waitcnt lgkmcnt(0)" ::: "memory")

// ---------------- fused cast f32 -> bf16: states (4096 blk) + bias (4096 blk) ----------
__global__ __launch_bounds__(256) void cast2_bf16_kernel(const float* __restrict__ in0,
                                                         unsigned short* __restrict__ out0,
                                                         const float* __restrict__ in1,
                                                         unsigned short* __restrict__ out1) {
  int bid = blockIdx.x;
  const float* in = (bid < 4096) ? in0 : in1;
  unsigned short* out = (bid < 4096) ? out0 : out1;
  int i = ((bid < 4096) ? bid : bid - 4096) * 256 + threadIdx.x;
  const float4* p = (const float4*)in;
  float4 a = p[2*i], b = p[2*i+1];
  us4 r0, r1;
  r0[0]=f2b(a.x); r0[1]=f2b(a.y); r0[2]=f2b(a.z); r0[3]=f2b(a.w);
  r1[0]=f2b(b.x); r1[1]=f2b(b.y); r1[2]=f2b(b.z); r1[3]=f2b(b.w);
  us4* o = (us4*)out;
  o[2*i] = r0; o[2*i+1] = r1;
}

// ---------------- fused transpose+cast: 4 x w[2048][2048] f32 -> wt = w^T bf16 ----------
__global__ __launch_bounds__(256) void transpose_cast4_kernel(const float* __restrict__ w0,
                                                              const float* __restrict__ w1,
                                                              const float* __restrict__ w2,
                                                              const float* __restrict__ w3,
                                                              unsigned short* __restrict__ dst) {
  const float* w = (blockIdx.z == 0) ? w0 : (blockIdx.z == 1) ? w1 : (blockIdx.z == 2) ? w2 : w3;
  unsigned short* wt = dst + (size_t)blockIdx.z * DM * DM;
  __shared__ float t[64][65];
  int c0 = blockIdx.x * 64, r0 = blockIdx.y * 64;
  int tid = threadIdx.x;
  int rr = tid >> 4;
  int c4 = (tid & 15) * 4;
#pragma unroll
  for (int p = 0; p < 4; ++p) {
    int r = p*16 + rr;
    float4 v = *(const float4*)&w[(size_t)(r0 + r)*DM + c0 + c4];
    t[r][c4] = v.x; t[r][c4+1] = v.y; t[r][c4+2] = v.z; t[r][c4+3] = v.w;
  }
  __syncthreads();
#pragma unroll
  for (int p = 0; p < 4; ++p) {
    int c = p*16 + rr;
    us4 v;
    v[0] = f2b(t[c4+0][c]); v[1] = f2b(t[c4+1][c]);
    v[2] = f2b(t[c4+2][c]); v[3] = f2b(t[c4+3][c]);
    *(us4*)&wt[(size_t)(c0 + c)*DM + r0 + c4] = v;
  }
}

// ---------------- transpose + cast wg[2048][16] f32 -> wgT[16][2048] bf16 ----------------
__global__ __launch_bounds__(256) void transpose_wg_kernel(const float* __restrict__ wg,
                                                           unsigned short* __restrict__ wgT) {
  int idx = blockIdx.x * 256 + threadIdx.x;
  int c = idx & 15;
  int r0 = (idx >> 4) * 4;
#pragma unroll
  for (int r = 0; r < 4; ++r)
    wgT[(size_t)c*DM + r0 + r] = f2b(wg[(size_t)(r0 + r)*NH + c]);
}

// ================= 128x128 / BK=64 / 4-wave / 2-phase GEMM core — 2 blocks/CU ===========
__device__ __forceinline__ void gemm128x128_core(const unsigned short* __restrict__ A,
                                                 const unsigned short* __restrict__ Bt,
                                                 int m0, int n0, f32x4 (&acc)[4][4]) {
  __shared__ __align__(16) unsigned short Ab[2][8192];
  __shared__ __align__(16) unsigned short Bb[2][8192];
  const int TK = DM / 64;   // 32 K-steps

  int tid = threadIdx.x, wid = tid >> 6, lane = tid & 63;
  int lo = lane & 15, hi = lane >> 4;
  int wm = wid >> 1, wn = wid & 1;

  int srow8 = lane >> 3;
  int skb = (((lane & 7) ^ srow8) << 4);
  const char* Ag = (const char*)A;
  const char* Bg = (const char*)Bt;

#define STG_A(S,CUR) do {                                                          \
    const char* g = Ag + (size_t)(S)*128 + skb;                                    \
    char* l = (char*)&Ab[CUR][0] + wid*4096;                                       \
    _Pragma("unroll")                                                              \
    for (int c = 0; c < 4; ++c)                                                    \
      gl_lds16(g + (size_t)(m0 + wid*32 + c*8 + srow8)*4096, l + c*1024);          \
  } while(0)
#define STG_B(S,CUR) do {                                                          \
    const char* g = Bg + (size_t)(S)*128 + skb;                                    \
    char* l = (char*)&Bb[CUR][0] + wid*4096;                                       \
    _Pragma("unroll")                                                              \
    for (int c = 0; c < 4; ++c)                                                    \
      gl_lds16(g + (size_t)(n0 + wid*32 + c*8 + srow8)*4096, l + c*1024);          \
  } while(0)

#pragma unroll
  for (int i = 0; i < 4; ++i)
#pragma unroll
    for (int j = 0; j < 4; ++j) acc[i][j] = (f32x4){0.f,0.f,0.f,0.f};

  STG_B(0,0); STG_A(0,0); STG_B(1,1); STG_A(1,1);
  asm volatile("s_waitcnt vmcnt(8)" ::: "memory");
  SBAR();

  int msk = (lo & 7) << 4;
  int k0 = (hi*16) ^ msk;
  int k1 = (64 + hi*16) ^ msk;

  short8 a[4][2], bA[2][2], bB[2][2];

#define MF16(NHH,BF)                                                                \
  __builtin_amdgcn_s_setprio(1);                                                    \
  _Pragma("unroll") for (int mi = 0; mi < 4; ++mi)                                  \
  _Pragma("unroll") for (int nn = 0; nn < 2; ++nn) {                                \
    acc[mi][(NHH)*2+nn] = __builtin_amdgcn_mfma_f32_16x16x32_bf16(                  \
        a[mi][0], BF[nn][0], acc[mi][(NHH)*2+nn], 0, 0, 0);                         \
    acc[mi][(NHH)*2+nn] = __builtin_amdgcn_mfma_f32_16x16x32_bf16(                  \
        a[mi][1], BF[nn][1], acc[mi][(NHH)*2+nn], 0, 0, 0);                         \
  }                                                                                 \
  __builtin_amdgcn_s_setprio(0);

  for (int s = 0; s < TK; ++s) {
    int cur = s & 1;
    const char* Ac = (const char*)&Ab[cur][0];
    const char* Bc = (const char*)&Bb[cur][0];
    bool pre = (s + 2) < TK;

#pragma unroll
    for (int mm = 0; mm < 4; ++mm) {
      a[mm][0] = *(const short8*)(Ac + (wm*64 + mm*16 + lo)*128 + k0);
      a[mm][1] = *(const short8*)(Ac + (wm*64 + mm*16 + lo)*128 + k1);
    }
#pragma unroll
    for (int nn = 0; nn < 2; ++nn) {
      bA[nn][0] = *(const short8*)(Bc + (wn*64 + nn*16 + lo)*128 + k0);
      bA[nn][1] = *(const short8*)(Bc + (wn*64 + nn*16 + lo)*128 + k1);
      bB[nn][0] = *(const short8*)(Bc + (wn*64 + (2+nn)*16 + lo)*128 + k0);
      bB[nn][1] = *(const short8*)(Bc + (wn*64 + (2+nn)*16 + lo)*128 + k1);
    }
    SBAR(); LGKM0(); SCHED0();
    MF16(0, bA);
    SBAR();

    if (pre) {
      STG_B(s + 2, cur);
      STG_A(s + 2, cur);
      asm volatile("s_waitcnt vmcnt(8)" ::: "memory");
    } else if (s == TK - 2) {
      asm volatile("s_waitcnt vmcnt(0)" ::: "memory");
    }
    SBAR();
    MF16(1, bB);
    SBAR();
  }
#undef STG_A
#undef STG_B
#undef MF16
}

// ---------------- fused QKV GEMM: A(4096x2048) x WQVT(6144x2048)^T, grid 48x32 --------
__global__ __launch_bounds__(256, 2) void gemm128_qkv_kernel(const unsigned short* __restrict__ A,
                                                             const unsigned short* __restrict__ Bt,
                                                             const float* __restrict__ bq,
                                                             const float* __restrict__ bk,
                                                             const float* __restrict__ bv,
                                                             unsigned short* __restrict__ QB,
                                                             unsigned short* __restrict__ KB,
                                                             unsigned short* __restrict__ VTB) {
  f32x4 acc[4][4];
  int n0 = blockIdx.x * 128, m0 = blockIdx.y * 128;
  gemm128x128_core(A, Bt, m0, n0, acc);

  int tid = threadIdx.x, wid = tid >> 6, lane = tid & 63;
  int lo = lane & 15, hi = lane >> 4;
  int wm = wid >> 1, wn = wid & 1;
  int m_base = m0 + wm*64;
  int n_base = n0 + wn*64;
  int sect = n0 >> 11;

  if (sect == 2) {       // V -> transposed [b,h,d,s]
#pragma unroll
    for (int mi = 0; mi < 4; ++mi) {
      int m = m_base + mi*16 + 4*hi;
      int b = m >> 11, srow = m & 2047;
#pragma unroll
      for (int nf = 0; nf < 4; ++nf) {
        int n = n_base + nf*16 + lo;
        int nl = n & 2047, h = nl >> 7, d = nl & 127;
        float bvv = bv[nl];
        us4 pk;
#pragma unroll
        for (int r = 0; r < 4; ++r) pk[r] = f2b(acc[mi][nf][r] + bvv);
        *(us4*)&VTB[(((size_t)(b*NH + h))*DK + d)*SEQ + srow] = pk;
      }
    }
  } else {
    unsigned short* out = sect ? KB : QB;
    const float* bp = sect ? bk : bq;
    const float qs = sect ? 1.f : QK_SCALE * LOG2E;
#pragma unroll
    for (int mi = 0; mi < 4; ++mi) {
#pragma unroll
      for (int nf = 0; nf < 4; ++nf) {
        int n = n_base + nf*16 + lo;
        int nl = n & 2047, h = nl >> 7, d = nl & 127;
        float bvv = bp[nl];
#pragma unroll
        for (int r = 0; r < 4; ++r) {
          int m = m_base + mi*16 + 4*hi + r;
          int b = m >> 11, srow = m & 2047;
          out[(((size_t)(b*NH + h))*SEQ + srow)*DK + d] = f2b((acc[mi][nf][r] + bvv) * qs);
        }
      }
    }
  }
}

// ---------------- AO GEMM: grid 16x32 = 512 blocks; f32 out + bias ----------------
__global__ __launch_bounds__(256, 2) void gemm128_ao_kernel(const unsigned short* __restrict__ A,
                                                            const unsigned short* __restrict__ Bt,
                                                            const float* __restrict__ bias,
                                                            float* __restrict__ out) {
  f32x4 acc[4][4];
  int n0 = blockIdx.x * 128, m0 = blockIdx.y * 128;
  gemm128x128_core(A, Bt, m0, n0, acc);

  int tid = threadIdx.x, wid = tid >> 6, lane = tid & 63;
  int lo = lane & 15, hi = lane >> 4;
  int wm = wid >> 1, wn = wid & 1;
#pragma unroll
  for (int mi = 0; mi < 4; ++mi) {
#pragma unroll
    for (int nf = 0; nf < 4; ++nf) {
      int n = n0 + wn*64 + nf*16 + lo;
      float bvv = bias[n];
#pragma unroll
      for (int r = 0; r < 4; ++r) {
        int m = m0 + wm*64 + mi*16 + 4*hi + r;
        out[(size_t)m*DM + n] = acc[mi][nf][r] + bvv;
      }
    }
  }
}

// ---------------- gate via MFMA: G[m][h] = sigmoid(XB[m]·wgT[h] + bg[h]) ----------------
__global__ __launch_bounds__(256) void gate_mfma_kernel(const unsigned short* __restrict__ XB,
                                                        const unsigned short* __restrict__ wgT,
                                                        const float* __restrict__ bg,
                                                        float* __restrict__ G) {
  int tid = threadIdx.x, wid = tid >> 6, lane = tid & 63;
  int lo = lane & 15, hi = lane >> 4;
  int m0 = blockIdx.x * 64 + wid * 16;

  f32x4 acc = {0.f, 0.f, 0.f, 0.f};
  const unsigned short* xrow = XB + (size_t)(m0 + lo) * DM + hi * 8;
  const unsigned short* grow = wgT + (size_t)lo * DM + hi * 8;
#pragma unroll 4
  for (int kt = 0; kt < DM; kt += 32) {
    short8 a = *(const short8*)(xrow + kt);
    short8 b = *(const short8*)(grow + kt);
    acc = __builtin_amdgcn_mfma_f32_16x16x32_bf16(a, b, acc, 0, 0, 0);
  }
  float bgv = bg[lo];
#pragma unroll
  for (int r = 0; r < 4; ++r) {
    float x = acc[r] + bgv;
    G[(size_t)(m0 + 4*hi + r) * NH + lo] = 1.f / (1.f + __builtin_amdgcn_exp2f(-x * LOG2E));
  }
}

// ---------------- flash attention v6 (r13-verified best): QBLK=256, 256 blocks ----------
__global__ __attribute__((amdgpu_flat_work_group_size(512,512)))
__attribute__((amdgpu_waves_per_eu(2,4)))
void attn_kernel(const unsigned short* __restrict__ Q,
                 const unsigned short* __restrict__ Kb,
                 const unsigned short* __restrict__ VT,
                 const unsigned short* __restrict__ biasb,
                 const float* __restrict__ G,
                 unsigned short* __restrict__ OG) {
  __shared__ __align__(16) unsigned short kbuf[2][64*128];   // [key][d] 256B rows, row-XOR swz
  __shared__ __align__(16) unsigned short vbuf[2][128*64];   // [d][key] 128B rows, row-XOR swz
  __shared__ __align__(16) unsigned short pbuf[8*16*64];     // per-wave P bf16 (reused per frag)

  int bid = blockIdx.x;
  int h  = bid & 15;
  int b  = (bid >> 4) & 1;
  int qt = bid >> 5;                      // 0..7
  int bh = b*NH + h;

  int tid = threadIdx.x, wid = tid >> 6, lane = tid & 63;
  int lo = lane & 15, hi = lane >> 4;
  int qw0 = qt*256 + wid*32;

  float hs2 = __builtin_amdgcn_exp2f(-(float)(h+1) * 0.5f) * LOG2E;

  short8 qf[2][4];
#pragma unroll
  for (int f2 = 0; f2 < 2; ++f2)
#pragma unroll
    for (int ks = 0; ks < 4; ++ks)
      qf[f2][ks] = *(const short8*)&Q[((size_t)bh*SEQ + qw0 + f2*16 + lo)*DK + ks*32 + hi*8];

  f32x4 zero4 = {0.f,0.f,0.f,0.f};
  f32x4 acco[2][8];
#pragma unroll
  for (int f2 = 0; f2 < 2; ++f2)
#pragma unroll
    for (int f = 0; f < 8; ++f) acco[f2][f] = zero4;
  float lrun[2][4];
#pragma unroll
  for (int f2 = 0; f2 < 2; ++f2)
#pragma unroll
    for (int r = 0; r < 4; ++r) lrun[f2][r] = 0.f;

  const char* kbase = (const char*)Kb + ((size_t)bh*SEQ)*DK*2;
  const char* vbase = (const char*)VT + ((size_t)bh*DK)*SEQ*2;
  const unsigned short* bb = biasb + ((size_t)b*SEQ + qw0 + 4*hi)*SEQ + lo;
  char* pb = (char*)pbuf + wid*2048;

  int s16 = lane >> 4, srow8 = lane >> 3;
  int kof = (lane & 15) * 16, vof = (lane & 7) * 16;
  int w2 = wid * 2;

#define STAGE_KV(KT, BUF) do {                                                        \
    _Pragma("unroll")                                                                 \
    for (int c = 0; c < 2; ++c) {                                                     \
      int krc = (w2 + c)*4 + s16;                                                     \
      gl_lds16(kbase + (size_t)((KT) + krc)*256 + (kof ^ ((krc & 7) << 4)),           \
               (char*)kbuf[BUF] + (w2 + c)*1024);                                     \
      int vrc = (w2 + c)*8 + srow8;                                                   \
      gl_lds16(vbase + (size_t)vrc*4096 + (size_t)(KT)*2 + (vof ^ (srow8 << 4)),      \
               (char*)vbuf[BUF] + (w2 + c)*1024);                                     \
    }                                                                                 \
  } while(0)

  unsigned short br[2][4][4];
#pragma unroll
  for (int f2 = 0; f2 < 2; ++f2)
#pragma unroll
    for (int r = 0; r < 4; ++r)
#pragma unroll
      for (int nf = 0; nf < 4; ++nf)
        br[f2][r][nf] = bb[(size_t)(f2*16 + r)*SEQ + nf*16];
  STAGE_KV(0, 0);
  STAGE_KV(64, 1);
  asm volatile("s_waitcnt vmcnt(4)" ::: "memory");   // bias(0)+KV(0) landed, KV(1) in flight
  SBAR();

  const int NT = SEQ / 64;
  int cur = 0;
  for (int t = 0; t < NT; ++t) {
#pragma unroll
    for (int f2 = 0; f2 < 2; ++f2) {
      // ---- QK^T fragment f2 from kbuf[cur] ----
      f32x4 sf[4];
      __builtin_amdgcn_s_setprio(1);
#pragma unroll
      for (int nf = 0; nf < 4; ++nf) {
        f32x4 a = zero4;
#pragma unroll
        for (int ks = 0; ks < 4; ++ks) {
          int krw = nf*16 + lo;
          int cb = (ks*32 + hi*8)*2;
          short8 kf = *(const short8*)((const char*)kbuf[cur] + krw*256 + (cb ^ ((krw & 7) << 4)));
          a = __builtin_amdgcn_mfma_f32_16x16x32_bf16(qf[f2][ks], kf, a, 0, 0, 0);
        }
        sf[nf] = a;
      }
      __builtin_amdgcn_s_setprio(0);

      // ---- direct exp2 softmax (no max), P into per-wave pbuf (reused per frag) ----
#pragma unroll
      for (int r = 0; r < 4; ++r) {
        int prow = 4*hi + r;
#pragma unroll
        for (int nf = 0; nf < 4; ++nf) {
          float s = fmaf(b2f(br[f2][r][nf]), hs2, sf[nf][r]);
          float p = __builtin_amdgcn_exp2f(s);
          lrun[f2][r] += p;
          *(unsigned short*)(pb + prow*128 + ((((nf*16 + lo)*2)) ^ ((prow & 7) << 4))) = f2b(p);
        }
      }

      // ---- PV fragment f2 from vbuf[cur] ----
      short8 pf[2];
#pragma unroll
      for (int ks = 0; ks < 2; ++ks)
        pf[ks] = *(const short8*)(pb + lo*128 + ((ks*64 + hi*16) ^ ((lo & 7) << 4)));
      __builtin_amdgcn_s_setprio(1);
#pragma unroll
      for (int f = 0; f < 8; ++f) {
#pragma unroll
        for (int ks = 0; ks < 2; ++ks) {
          int vrw = f*16 + lo;
          int cb = (ks*32 + hi*8)*2;
          short8 vf = *(const short8*)((const char*)vbuf[cur] + vrw*128 + (cb ^ ((vrw & 7) << 4)));
          acco[f2][f] = __builtin_amdgcn_mfma_f32_16x16x32_bf16(pf[ks], vf, acco[f2][f], 0, 0, 0);
        }
      }
      __builtin_amdgcn_s_setprio(0);
    }

    LGKM0(); SBAR();                    // B2: all waves done reading kbuf/vbuf[cur]

    bool more1 = (t + 1) < NT;
    bool more2 = (t + 2) < NT;
    if (more1) {                         // bias(t+1): issued BEFORE next K/V stage (older)
      int ktn = (t + 1) * 64;
#pragma unroll
      for (int f2 = 0; f2 < 2; ++f2)
#pragma unroll
        for (int r = 0; r < 4; ++r)
#pragma unroll
          for (int nf = 0; nf < 4; ++nf)
            br[f2][r][nf] = bb[(size_t)(f2*16 + r)*SEQ + ktn + nf*16];
    }
    if (more2) {
      STAGE_KV((t + 2) * 64, cur);
      asm volatile("s_waitcnt vmcnt(36)" ::: "memory");  // KV(t+1) landed; 32 bias + 4 KV fly
    } else if (more1) {
      asm volatile("s_waitcnt vmcnt(32)" ::: "memory");  // KV(t+1) landed; 32 bias fly
    }
    SBAR();                             // B3: tile t+1 visible to all waves
    cur ^= 1;
  }
#undef STAGE_KV

  // ---- final l reduction over lo-lanes (once) ----
#pragma unroll
  for (int f2 = 0; f2 < 2; ++f2)
#pragma unroll
    for (int r = 0; r < 4; ++r) {
      float l = lrun[f2][r];
      l += __shfl_xor(l, 1); l += __shfl_xor(l, 2);
      l += __shfl_xor(l, 4); l += __shfl_xor(l, 8);
      lrun[f2][r] = l;
    }

  // ---- epilogue: normalize, gate, write OG[b,s, h*128+d] bf16 ----
#pragma unroll
  for (int f2 = 0; f2 < 2; ++f2)
#pragma unroll
    for (int r = 0; r < 4; ++r) {
      int qrow = qw0 + f2*16 + 4*hi + r;
      float inv = 1.f / lrun[f2][r];
      float g = G[((size_t)(b*SEQ + qrow))*NH + h];
      float sgl = inv * g;
#pragma unroll
      for (int f = 0; f < 8; ++f)
        OG[((size_t)(b*SEQ) + qrow)*DM + h*DK + f*16 + lo] = f2b(acco[f2][f][r] * sgl);
    }
}

// ---------------- launcher ----------------
extern "C" void kernel_launch(void* const* d_in, const int* in_sizes, int n_in,
                              void* d_out, int out_size, void* d_ws, size_t ws_size,
                              hipStream_t stream) {
  const float* states    = (const float*)d_in[0];
  const float* bias_mask = (const float*)d_in[1];
  const float* wq = (const float*)d_in[2];
  const float* bq = (const float*)d_in[3];
  const float* wk = (const float*)d_in[4];
  const float* bk = (const float*)d_in[5];
  const float* wv = (const float*)d_in[6];
  const float* bv = (const float*)d_in[7];
  const float* wg = (const float*)d_in[8];
  const float* bg = (const float*)d_in[9];
  const float* wo = (const float*)d_in[10];
  const float* bo = (const float*)d_in[11];

  char* ws = (char*)d_ws;
  unsigned short* XB   = (unsigned short*)(ws + 0);              // aliased by OGB later
  unsigned short* OGB  = XB;
  unsigned short* WQVT = (unsigned short*)(ws + 16777216UL);     // 4 x 8.39MB contiguous (Q,K,V,O)
  unsigned short* WOT  = (unsigned short*)(ws + 41943040UL);
  unsigned short* QB   = (unsigned short*)(ws + 50331648UL);
  unsigned short* KB   = (unsigned short*)(ws + 67108864UL);
  unsigned short* VTB  = (unsigned short*)(ws + 83886080UL);
  unsigned short* BIASB= (unsigned short*)(ws + 100663296UL);
  float*          GB   = (float*)         (ws + 117440512UL);
  unsigned short* WGT  = (unsigned short*)(ws + 117702656UL);    // 64 KB

  cast2_bf16_kernel<<<8192, 256, 0, stream>>>(states, XB, bias_mask, BIASB);
  transpose_cast4_kernel<<<dim3(32, 32, 4), 256, 0, stream>>>(wq, wk, wv, wo, WQVT);
  transpose_wg_kernel<<<32, 256, 0, stream>>>(wg, WGT);

  gemm128_qkv_kernel<<<dim3(48, 32), 256, 0, stream>>>(XB, WQVT, bq, bk, bv, QB, KB, VTB);

  gate_mfma_kernel<<<64, 256, 0, stream>>>(XB, WGT, bg, GB);

  attn_kernel<<<256, 512, 0, stream>>>(QB, KB, VTB, BIASB, GB, OGB);

  gemm128_ao_kernel<<<dim3(16, 32), 256, 0, stream>>>(OGB, WOT, bo, (float*)d_out);
}

// Round 18
// 310.289 us; speedup vs baseline: 1.2364x; 1.0392x over previous
//
#include <hip/hip_runtime.h>
#include <hip/hip_bf16.h>

#define SEQ 2048
#define DM 2048
#define NH 16
#define DK 128
#define LOG2E 1.4426950408889634f
#define QK_SCALE 0.08838834764831845f   // 128^-0.5

typedef __attribute__((ext_vector_type(8))) short short8;
typedef __attribute__((ext_vector_type(4))) float f32x4;
typedef __attribute__((ext_vector_type(4))) unsigned short us4;

__device__ __forceinline__ unsigned short f2b(float f) {
  union { float f; unsigned u; } v; v.f = f;
  unsigned r = v.u + 0x7fffu + ((v.u >> 16) & 1u);
  return (unsigned short)(r >> 16);
}
__device__ __forceinline__ float b2f(unsigned short v) {
  union { unsigned u; float f; } x; x.u = ((unsigned)v) << 16; return x.f;
}

__device__ __forceinline__ void gl_lds16(const void* g, void* l) {
  __builtin_amdgcn_global_load_lds((const __attribute__((address_space(1))) void*)g,
                                   (__attribute__((address_space(3))) void*)l, 16, 0, 0);
}

#define SBAR()   __builtin_amdgcn_s_barrier()
#define SCHED0() __builtin_amdgcn_sched_barrier(0)
#define LGKM0()  asm volatile("s_waitcnt lgkmcnt(0)" ::: "memory")

// ============ fused prep: casts (states+bias) | 4x weight transpose | wg transpose ======
// grid 12320 x 256: [0,8192) cast, [8192,12288) transpose4, [12288,12320) wg
__global__ __launch_bounds__(256) void prep_kernel(const float* __restrict__ states,
                                                   unsigned short* __restrict__ XB,
                                                   const float* __restrict__ bias_mask,
                                                   unsigned short* __restrict__ BIASB,
                                                   const float* __restrict__ w0,
                                                   const float* __restrict__ w1,
                                                   const float* __restrict__ w2,
                                                   const float* __restrict__ w3,
                                                   unsigned short* __restrict__ WT,
                                                   const float* __restrict__ wg,
                                                   unsigned short* __restrict__ wgT) {
  int bid = blockIdx.x;
  if (bid < 8192) {
    const float* in = (bid < 4096) ? states : bias_mask;
    unsigned short* out = (bid < 4096) ? XB : BIASB;
    int i = ((bid < 4096) ? bid : bid - 4096) * 256 + threadIdx.x;
    const float4* p = (const float4*)in;
    float4 a = p[2*i], b = p[2*i+1];
    us4 r0, r1;
    r0[0]=f2b(a.x); r0[1]=f2b(a.y); r0[2]=f2b(a.z); r0[3]=f2b(a.w);
    r1[0]=f2b(b.x); r1[1]=f2b(b.y); r1[2]=f2b(b.z); r1[3]=f2b(b.w);
    us4* o = (us4*)out;
    o[2*i] = r0; o[2*i+1] = r1;
  } else if (bid < 12288) {
    int t = bid - 8192;
    int z = t >> 10, rem = t & 1023;
    int r0 = (rem >> 5) * 64, c0 = (rem & 31) * 64;
    const float* w = (z == 0) ? w0 : (z == 1) ? w1 : (z == 2) ? w2 : w3;
    unsigned short* wt = WT + (size_t)z * DM * DM;
    __shared__ float tbuf[64][65];
    int tid = threadIdx.x;
    int rr = tid >> 4;
    int c4 = (tid & 15) * 4;
#pragma unroll
    for (int p = 0; p < 4; ++p) {
      int r = p*16 + rr;
      float4 v = *(const float4*)&w[(size_t)(r0 + r)*DM + c0 + c4];
      tbuf[r][c4] = v.x; tbuf[r][c4+1] = v.y; tbuf[r][c4+2] = v.z; tbuf[r][c4+3] = v.w;
    }
    __syncthreads();
#pragma unroll
    for (int p = 0; p < 4; ++p) {
      int c = p*16 + rr;
      us4 v;
      v[0] = f2b(tbuf[c4+0][c]); v[1] = f2b(tbuf[c4+1][c]);
      v[2] = f2b(tbuf[c4+2][c]); v[3] = f2b(tbuf[c4+3][c]);
      *(us4*)&wt[(size_t)(c0 + c)*DM + r0 + c4] = v;
    }
  } else {
    int idx = (bid - 12288) * 256 + threadIdx.x;
    int c = idx & 15;
    int r0 = (idx >> 4) * 4;
#pragma unroll
    for (int r = 0; r < 4; ++r)
      wgT[(size_t)c*DM + r0 + r] = f2b(wg[(size_t)(r0 + r)*NH + c]);
  }
}

// ================= 128x128 / BK=64 / 4-wave / 2-phase GEMM core — 2 blocks/CU ===========
__device__ __forceinline__ void gemm128x128_core(const unsigned short* __restrict__ A,
                                                 const unsigned short* __restrict__ Bt,
                                                 int m0, int n0, f32x4 (&acc)[4][4]) {
  __shared__ __align__(16) unsigned short Ab[2][8192];
  __shared__ __align__(16) unsigned short Bb[2][8192];
  const int TK = DM / 64;   // 32 K-steps

  int tid = threadIdx.x, wid = tid >> 6, lane = tid & 63;
  int lo = lane & 15, hi = lane >> 4;
  int wm = wid >> 1, wn = wid & 1;

  int srow8 = lane >> 3;
  int skb = (((lane & 7) ^ srow8) << 4);
  const char* Ag = (const char*)A;
  const char* Bg = (const char*)Bt;

#define STG_A(S,CUR) do {                                                          \
    const char* g = Ag + (size_t)(S)*128 + skb;                                    \
    char* l = (char*)&Ab[CUR][0] + wid*4096;                                       \
    _Pragma("unroll")                                                              \
    for (int c = 0; c < 4; ++c)                                                    \
      gl_lds16(g + (size_t)(m0 + wid*32 + c*8 + srow8)*4096, l + c*1024);          \
  } while(0)
#define STG_B(S,CUR) do {                                                          \
    const char* g = Bg + (size_t)(S)*128 + skb;                                    \
    char* l = (char*)&Bb[CUR][0] + wid*4096;                                       \
    _Pragma("unroll")                                                              \
    for (int c = 0; c < 4; ++c)                                                    \
      gl_lds16(g + (size_t)(n0 + wid*32 + c*8 + srow8)*4096, l + c*1024);          \
  } while(0)

#pragma unroll
  for (int i = 0; i < 4; ++i)
#pragma unroll
    for (int j = 0; j < 4; ++j) acc[i][j] = (f32x4){0.f,0.f,0.f,0.f};

  STG_B(0,0); STG_A(0,0); STG_B(1,1); STG_A(1,1);
  asm volatile("s_waitcnt vmcnt(8)" ::: "memory");
  SBAR();

  int msk = (lo & 7) << 4;
  int k0 = (hi*16) ^ msk;
  int k1 = (64 + hi*16) ^ msk;

  short8 a[4][2], bA[2][2], bB[2][2];

#define MF16(NHH,BF)                                                                \
  __builtin_amdgcn_s_setprio(1);                                                    \
  _Pragma("unroll") for (int mi = 0; mi < 4; ++mi)                                  \
  _Pragma("unroll") for (int nn = 0; nn < 2; ++nn) {                                \
    acc[mi][(NHH)*2+nn] = __builtin_amdgcn_mfma_f32_16x16x32_bf16(                  \
        a[mi][0], BF[nn][0], acc[mi][(NHH)*2+nn], 0, 0, 0);                         \
    acc[mi][(NHH)*2+nn] = __builtin_amdgcn_mfma_f32_16x16x32_bf16(                  \
        a[mi][1], BF[nn][1], acc[mi][(NHH)*2+nn], 0, 0, 0);                         \
  }                                                                                 \
  __builtin_amdgcn_s_setprio(0);

  for (int s = 0; s < TK; ++s) {
    int cur = s & 1;
    const char* Ac = (const char*)&Ab[cur][0];
    const char* Bc = (const char*)&Bb[cur][0];
    bool pre = (s + 2) < TK;

#pragma unroll
    for (int mm = 0; mm < 4; ++mm) {
      a[mm][0] = *(const short8*)(Ac + (wm*64 + mm*16 + lo)*128 + k0);
      a[mm][1] = *(const short8*)(Ac + (wm*64 + mm*16 + lo)*128 + k1);
    }
#pragma unroll
    for (int nn = 0; nn < 2; ++nn) {
      bA[nn][0] = *(const short8*)(Bc + (wn*64 + nn*16 + lo)*128 + k0);
      bA[nn][1] = *(const short8*)(Bc + (wn*64 + nn*16 + lo)*128 + k1);
      bB[nn][0] = *(const short8*)(Bc + (wn*64 + (2+nn)*16 + lo)*128 + k0);
      bB[nn][1] = *(const short8*)(Bc + (wn*64 + (2+nn)*16 + lo)*128 + k1);
    }
    SBAR(); LGKM0(); SCHED0();
    MF16(0, bA);
    SBAR();

    if (pre) {
      STG_B(s + 2, cur);
      STG_A(s + 2, cur);
      asm volatile("s_waitcnt vmcnt(8)" ::: "memory");
    } else if (s == TK - 2) {
      asm volatile("s_waitcnt vmcnt(0)" ::: "memory");
    }
    SBAR();
    MF16(1, bB);
    SBAR();
  }
#undef STG_A
#undef STG_B
#undef MF16
}

// ---------------- fused QKV GEMM + gate: grid 1600 (first 64 = gate, rest 1536 GEMM) ----
__global__ __launch_bounds__(256, 2) void gemm128_qkv_kernel(const unsigned short* __restrict__ A,
                                                             const unsigned short* __restrict__ Bt,
                                                             const float* __restrict__ bq,
                                                             const float* __restrict__ bk,
                                                             const float* __restrict__ bv,
                                                             unsigned short* __restrict__ QB,
                                                             unsigned short* __restrict__ KB,
                                                             unsigned short* __restrict__ VTB,
                                                             const unsigned short* __restrict__ wgT,
                                                             const float* __restrict__ bg,
                                                             float* __restrict__ G) {
  int tid = threadIdx.x, wid = tid >> 6, lane = tid & 63;
  int lo = lane & 15, hi = lane >> 4;

  if (blockIdx.x < 64) {   // ---- gate path: G[m][h] = sigmoid(A[m]·wgT[h] + bg[h]) ----
    int m0 = blockIdx.x * 64 + wid * 16;
    f32x4 gacc = {0.f, 0.f, 0.f, 0.f};
    const unsigned short* xrow = A + (size_t)(m0 + lo) * DM + hi * 8;
    const unsigned short* grow = wgT + (size_t)lo * DM + hi * 8;
#pragma unroll 4
    for (int kt = 0; kt < DM; kt += 32) {
      short8 av = *(const short8*)(xrow + kt);
      short8 bv2 = *(const short8*)(grow + kt);
      gacc = __builtin_amdgcn_mfma_f32_16x16x32_bf16(av, bv2, gacc, 0, 0, 0);
    }
    float bgv = bg[lo];
#pragma unroll
    for (int r = 0; r < 4; ++r) {
      float x = gacc[r] + bgv;
      G[(size_t)(m0 + 4*hi + r) * NH + lo] = 1.f / (1.f + __builtin_amdgcn_exp2f(-x * LOG2E));
    }
    return;
  }

  int bid = blockIdx.x - 64;
  int n0 = (bid % 48) * 128, m0 = (bid / 48) * 128;
  f32x4 acc[4][4];
  gemm128x128_core(A, Bt, m0, n0, acc);

  int wm = wid >> 1, wn = wid & 1;
  int m_base = m0 + wm*64;
  int n_base = n0 + wn*64;
  int sect = n0 >> 11;

  if (sect == 2) {       // V -> transposed [b,h,d,s]
#pragma unroll
    for (int mi = 0; mi < 4; ++mi) {
      int m = m_base + mi*16 + 4*hi;
      int b = m >> 11, srow = m & 2047;
#pragma unroll
      for (int nf = 0; nf < 4; ++nf) {
        int n = n_base + nf*16 + lo;
        int nl = n & 2047, h = nl >> 7, d = nl & 127;
        float bvv = bv[nl];
        us4 pk;
#pragma unroll
        for (int r = 0; r < 4; ++r) pk[r] = f2b(acc[mi][nf][r] + bvv);
        *(us4*)&VTB[(((size_t)(b*NH + h))*DK + d)*SEQ + srow] = pk;
      }
    }
  } else {
    unsigned short* out = sect ? KB : QB;
    const float* bp = sect ? bk : bq;
    const float qs = sect ? 1.f : QK_SCALE * LOG2E;
#pragma unroll
    for (int mi = 0; mi < 4; ++mi) {
#pragma unroll
      for (int nf = 0; nf < 4; ++nf) {
        int n = n_base + nf*16 + lo;
        int nl = n & 2047, h = nl >> 7, d = nl & 127;
        float bvv = bp[nl];
#pragma unroll
        for (int r = 0; r < 4; ++r) {
          int m = m_base + mi*16 + 4*hi + r;
          int b = m >> 11, srow = m & 2047;
          out[(((size_t)(b*NH + h))*SEQ + srow)*DK + d] = f2b((acc[mi][nf][r] + bvv) * qs);
        }
      }
    }
  }
}

// ---------------- AO GEMM: grid 16x32 = 512 blocks; f32 out + bias ----------------
__global__ __launch_bounds__(256, 2) void gemm128_ao_kernel(const unsigned short* __restrict__ A,
                                                            const unsigned short* __restrict__ Bt,
                                                            const float* __restrict__ bias,
                                                            float* __restrict__ out) {
  f32x4 acc[4][4];
  int n0 = blockIdx.x * 128, m0 = blockIdx.y * 128;
  gemm128x128_core(A, Bt, m0, n0, acc);

  int tid = threadIdx.x, wid = tid >> 6, lane = tid & 63;
  int lo = lane & 15, hi = lane >> 4;
  int wm = wid >> 1, wn = wid & 1;
#pragma unroll
  for (int mi = 0; mi < 4; ++mi) {
#pragma unroll
    for (int nf = 0; nf < 4; ++nf) {
      int n = n0 + wn*64 + nf*16 + lo;
      float bvv = bias[n];
#pragma unroll
      for (int r = 0; r < 4; ++r) {
        int m = m0 + wm*64 + mi*16 + 4*hi + r;
        out[(size_t)m*DM + n] = acc[mi][nf][r] + bvv;
      }
    }
  }
}

// ---------------- flash attention v6 (r13/r17-verified best): QBLK=256, 256 blocks ------
__global__ __attribute__((amdgpu_flat_work_group_size(512,512)))
__attribute__((amdgpu_waves_per_eu(2,4)))
void attn_kernel(const unsigned short* __restrict__ Q,
                 const unsigned short* __restrict__ Kb,
                 const unsigned short* __restrict__ VT,
                 const unsigned short* __restrict__ biasb,
                 const float* __restrict__ G,
                 unsigned short* __restrict__ OG) {
  __shared__ __align__(16) unsigned short kbuf[2][64*128];   // [key][d] 256B rows, row-XOR swz
  __shared__ __align__(16) unsigned short vbuf[2][128*64];   // [d][key] 128B rows, row-XOR swz
  __shared__ __align__(16) unsigned short pbuf[8*16*64];     // per-wave P bf16 (reused per frag)

  int bid = blockIdx.x;
  int h  = bid & 15;
  int b  = (bid >> 4) & 1;
  int qt = bid >> 5;                      // 0..7
  int bh = b*NH + h;

  int tid = threadIdx.x, wid = tid >> 6, lane = tid & 63;
  int lo = lane & 15, hi = lane >> 4;
  int qw0 = qt*256 + wid*32;

  float hs2 = __builtin_amdgcn_exp2f(-(float)(h+1) * 0.5f) * LOG2E;

  short8 qf[2][4];
#pragma unroll
  for (int f2 = 0; f2 < 2; ++f2)
#pragma unroll
    for (int ks = 0; ks < 4; ++ks)
      qf[f2][ks] = *(const short8*)&Q[((size_t)bh*SEQ + qw0 + f2*16 + lo)*DK + ks*32 + hi*8];

  f32x4 zero4 = {0.f,0.f,0.f,0.f};
  f32x4 acco[2][8];
#pragma unroll
  for (int f2 = 0; f2 < 2; ++f2)
#pragma unroll
    for (int f = 0; f < 8; ++f) acco[f2][f] = zero4;
  float lrun[2][4];
#pragma unroll
  for (int f2 = 0; f2 < 2; ++f2)
#pragma unroll
    for (int r = 0; r < 4; ++r) lrun[f2][r] = 0.f;

  const char* kbase = (const char*)Kb + ((size_t)bh*SEQ)*DK*2;
  const char* vbase = (const char*)VT + ((size_t)bh*DK)*SEQ*2;
  const unsigned short* bb = biasb + ((size_t)b*SEQ + qw0 + 4*hi)*SEQ + lo;
  char* pb = (char*)pbuf + wid*2048;

  int s16 = lane >> 4, srow8 = lane >> 3;
  int kof = (lane & 15) * 16, vof = (lane & 7) * 16;
  int w2 = wid * 2;

#define STAGE_KV(KT, BUF) do {                                                        \
    _Pragma("unroll")                                                                 \
    for (int c = 0; c < 2; ++c) {                                                     \
      int krc = (w2 + c)*4 + s16;                                                     \
      gl_lds16(kbase + (size_t)((KT) + krc)*256 + (kof ^ ((krc & 7) << 4)),           \
               (char*)kbuf[BUF] + (w2 + c)*1024);                                     \
      int vrc = (w2 + c)*8 + srow8;                                                   \
      gl_lds16(vbase + (size_t)vrc*4096 + (size_t)(KT)*2 + (vof ^ (srow8 << 4)),      \
               (char*)vbuf[BUF] + (w2 + c)*1024);                                     \
    }                                                                                 \
  } while(0)

  unsigned short br[2][4][4];
#pragma unroll
  for (int f2 = 0; f2 < 2; ++f2)
#pragma unroll
    for (int r = 0; r < 4; ++r)
#pragma unroll
      for (int nf = 0; nf < 4; ++nf)
        br[f2][r][nf] = bb[(size_t)(f2*16 + r)*SEQ + nf*16];
  STAGE_KV(0, 0);
  STAGE_KV(64, 1);
  asm volatile("s_waitcnt vmcnt(4)" ::: "memory");   // bias(0)+KV(0) landed, KV(1) in flight
  SBAR();

  const int NT = SEQ / 64;
  int cur = 0;
  for (int t = 0; t < NT; ++t) {
#pragma unroll
    for (int f2 = 0; f2 < 2; ++f2) {
      // ---- QK^T fragment f2 from kbuf[cur] ----
      f32x4 sf[4];
      __builtin_amdgcn_s_setprio(1);
#pragma unroll
      for (int nf = 0; nf < 4; ++nf) {
        f32x4 a = zero4;
#pragma unroll
        for (int ks = 0; ks < 4; ++ks) {
          int krw = nf*16 + lo;
          int cb = (ks*32 + hi*8)*2;
          short8 kf = *(const short8*)((const char*)kbuf[cur] + krw*256 + (cb ^ ((krw & 7) << 4)));
          a = __builtin_amdgcn_mfma_f32_16x16x32_bf16(qf[f2][ks], kf, a, 0, 0, 0);
        }
        sf[nf] = a;
      }
      __builtin_amdgcn_s_setprio(0);

      // ---- direct exp2 softmax (no max), P into per-wave pbuf (reused per frag) ----
#pragma unroll
      for (int r = 0; r < 4; ++r) {
        int prow = 4*hi + r;
#pragma unroll
        for (int nf = 0; nf < 4; ++nf) {
          float s = fmaf(b2f(br[f2][r][nf]), hs2, sf[nf][r]);
          float p = __builtin_amdgcn_exp2f(s);
          lrun[f2][r] += p;
          *(unsigned short*)(pb + prow*128 + ((((nf*16 + lo)*2)) ^ ((prow & 7) << 4))) = f2b(p);
        }
      }

      // ---- PV fragment f2 from vbuf[cur] ----
      short8 pf[2];
#pragma unroll
      for (int ks = 0; ks < 2; ++ks)
        pf[ks] = *(const short8*)(pb + lo*128 + ((ks*64 + hi*16) ^ ((lo & 7) << 4)));
      __builtin_amdgcn_s_setprio(1);
#pragma unroll
      for (int f = 0; f < 8; ++f) {
#pragma unroll
        for (int ks = 0; ks < 2; ++ks) {
          int vrw = f*16 + lo;
          int cb = (ks*32 + hi*8)*2;
          short8 vf = *(const short8*)((const char*)vbuf[cur] + vrw*128 + (cb ^ ((vrw & 7) << 4)));
          acco[f2][f] = __builtin_amdgcn_mfma_f32_16x16x32_bf16(pf[ks], vf, acco[f2][f], 0, 0, 0);
        }
      }
      __builtin_amdgcn_s_setprio(0);
    }

    LGKM0(); SBAR();                    // B2: all waves done reading kbuf/vbuf[cur]

    bool more1 = (t + 1) < NT;
    bool more2 = (t + 2) < NT;
    if (more1) {                         // bias(t+1): issued BEFORE next K/V stage (older)
      int ktn = (t + 1) * 64;
#pragma unroll
      for (int f2 = 0; f2 < 2; ++f2)
#pragma unroll
        for (int r = 0; r < 4; ++r)
#pragma unroll
          for (int nf = 0; nf < 4; ++nf)
            br[f2][r][nf] = bb[(size_t)(f2*16 + r)*SEQ + ktn + nf*16];
    }
    if (more2) {
      STAGE_KV((t + 2) * 64, cur);
      asm volatile("s_waitcnt vmcnt(36)" ::: "memory");  // KV(t+1) landed; 32 bias + 4 KV fly
    } else if (more1) {
      asm volatile("s_waitcnt vmcnt(32)" ::: "memory");  // KV(t+1) landed; 32 bias fly
    }
    SBAR();                             // B3: tile t+1 visible to all waves
    cur ^= 1;
  }
#undef STAGE_KV

  // ---- final l reduction over lo-lanes (once) ----
#pragma unroll
  for (int f2 = 0; f2 < 2; ++f2)
#pragma unroll
    for (int r = 0; r < 4; ++r) {
      float l = lrun[f2][r];
      l += __shfl_xor(l, 1); l += __shfl_xor(l, 2);
      l += __shfl_xor(l, 4); l += __shfl_xor(l, 8);
      lrun[f2][r] = l;
    }

  // ---- epilogue: normalize, gate, write OG[b,s, h*128+d] bf16 ----
#pragma unroll
  for (int f2 = 0; f2 < 2; ++f2)
#pragma unroll
    for (int r = 0; r < 4; ++r) {
      int qrow = qw0 + f2*16 + 4*hi + r;
      float inv = 1.f / lrun[f2][r];
      float g = G[((size_t)(b*SEQ + qrow))*NH + h];
      float sgl = inv * g;
#pragma unroll
      for (int f = 0; f < 8; ++f)
        OG[((size_t)(b*SEQ) + qrow)*DM + h*DK + f*16 + lo] = f2b(acco[f2][f][r] * sgl);
    }
}

// ---------------- launcher ----------------
extern "C" void kernel_launch(void* const* d_in, const int* in_sizes, int n_in,
                              void* d_out, int out_size, void* d_ws, size_t ws_size,
                              hipStream_t stream) {
  const float* states    = (const float*)d_in[0];
  const float* bias_mask = (const float*)d_in[1];
  const float* wq = (const float*)d_in[2];
  const float* bq = (const float*)d_in[3];
  const float* wk = (const float*)d_in[4];
  const float* bk = (const float*)d_in[5];
  const float* wv = (const float*)d_in[6];
  const float* bv = (const float*)d_in[7];
  const float* wg = (const float*)d_in[8];
  const float* bg = (const float*)d_in[9];
  const float* wo = (const float*)d_in[10];
  const float* bo = (const float*)d_in[11];

  char* ws = (char*)d_ws;
  unsigned short* XB   = (unsigned short*)(ws + 0);              // aliased by OGB later
  unsigned short* OGB  = XB;
  unsigned short* WQVT = (unsigned short*)(ws + 16777216UL);     // 4 x 8.39MB contiguous (Q,K,V,O)
  unsigned short* WOT  = (unsigned short*)(ws + 41943040UL);
  unsigned short* QB   = (unsigned short*)(ws + 50331648UL);
  unsigned short* KB   = (unsigned short*)(ws + 67108864UL);
  unsigned short* VTB  = (unsigned short*)(ws + 83886080UL);
  unsigned short* BIASB= (unsigned short*)(ws + 100663296UL);
  float*          GB   = (float*)         (ws + 117440512UL);
  unsigned short* WGT  = (unsigned short*)(ws + 117702656UL);    // 64 KB

  prep_kernel<<<12320, 256, 0, stream>>>(states, XB, bias_mask, BIASB,
                                         wq, wk, wv, wo, WQVT, wg, WGT);

  gemm128_qkv_kernel<<<1600, 256, 0, stream>>>(XB, WQVT, bq, bk, bv, QB, KB, VTB,
                                               WGT, bg, GB);

  attn_kernel<<<256, 512, 0, stream>>>(QB, KB, VTB, BIASB, GB, OGB);

  gemm128_ao_kernel<<<dim3(16, 32), 256, 0, stream>>>(OGB, WOT, bo, (float*)d_out);
}